// Round 5
// baseline (1076.072 us; speedup 1.0000x reference)
//
#include <hip/hip_runtime.h>
#include <hip/hip_bf16.h>

#define F_DIM 128
#define N_RBF 20
#define CUTOFF 5.0f
#define PI_F 3.14159265358979323846f
#define NPB 4   // nodes per k_edge block

typedef float v2f __attribute__((ext_vector_type(2)));

// ---------------------------------------------------------------------------
__global__ __launch_bounds__(256) void k_rowptr(const int* __restrict__ idx_i,
                                                int* __restrict__ row_ptr, int N, int E) {
    int i = blockIdx.x * blockDim.x + threadIdx.x;
    if (i > N) return;
    if (i == N) { row_ptr[N] = E; return; }
    int lo = 0, hi = E;
    while (lo < hi) {
        int mid = (lo + hi) >> 1;
        if (idx_i[mid] < i) lo = mid + 1; else hi = mid;
    }
    row_ptr[i] = lo;
}

// ---------------------------------------------------------------------------
// q = embedding[Z];  P = 0  (P: [N][128][6] packed gather records)
__global__ __launch_bounds__(256) void k_init(const int* __restrict__ Z,
                                              const float* __restrict__ emb,
                                              float* __restrict__ q,
                                              float* __restrict__ P, int N) {
    int idx = blockIdx.x * blockDim.x + threadIdx.x;
    if (idx < N * F_DIM) {
        int n = idx >> 7, f = idx & 127;
        q[idx] = emb[Z[n] * F_DIM + f];
    }
    if (idx < N * 768) P[idx] = 0.f;
}

// ---------------------------------------------------------------------------
__global__ __launch_bounds__(256) void k_geom(const float* __restrict__ r,
                                              float* __restrict__ geom, int E) {
    int e = blockIdx.x * blockDim.x + threadIdx.x;
    if (e >= E) return;
    float x = r[e * 3], y = r[e * 3 + 1], z = r[e * 3 + 2];
    float d = sqrtf(x * x + y * y + z * z);
    float inv = 1.f / d;
    float fc = (d < CUTOFF) ? 0.5f * (__cosf(d * (PI_F / CUTOFF)) + 1.f) : 0.f;
    float* g = geom + (size_t)e * 24;
    g[0] = x * inv; g[1] = y * inv; g[2] = z * inv; g[3] = fc;
    const float delta = CUTOFF / (N_RBF - 1);
    const float coeff = -0.5f / (delta * delta);
#pragma unroll
    for (int k = 0; k < N_RBF; k++) {
        float t = d - k * delta;
        g[4 + k] = __expf(coeff * t * t) * fc;
    }
}

// ---------------------------------------------------------------------------
// x = silu(q@W1 + b1)@W2 + b2   8 nodes/block (1250 blocks for TLP).
// Writes the x-part of P records: P[n][f][0..2].
__global__ __launch_bounds__(256) void k_node_msg(const float* __restrict__ q,
                                                  const float* __restrict__ W1,
                                                  const float* __restrict__ b1,
                                                  const float* __restrict__ W2,
                                                  const float* __restrict__ b2,
                                                  float* __restrict__ P, int N) {
    __shared__ float qs[8][128];
    __shared__ float hs[8][128];
    int n0 = blockIdx.x * 8;
    int t = threadIdx.x;
    int f = t & 127, nb = t >> 7;

    for (int r = 0; r < 4; r++) {
        int idx = r * 256 + t;
        int n = idx >> 7, ff = idx & 127;
        int gn = n0 + n;
        qs[n][ff] = (gn < N) ? q[(size_t)gn * 128 + ff] : 0.f;
    }
    __syncthreads();

    {   // h = silu(q@W1 + b1)
        float acc[4];
#pragma unroll
        for (int r = 0; r < 4; r++) acc[r] = b1[f];
        for (int k = 0; k < 128; k++) {
            float w = W1[k * 128 + f];
#pragma unroll
            for (int r = 0; r < 4; r++) acc[r] += qs[2 * r + nb][k] * w;
        }
#pragma unroll
        for (int r = 0; r < 4; r++) {
            float a = acc[r];
            hs[2 * r + nb][f] = a / (1.f + __expf(-a));
        }
    }
    __syncthreads();

    {   // x = h@W2 + b2  -> P[gn][f][0..2]
        float x0[4], x1[4], x2[4];
#pragma unroll
        for (int r = 0; r < 4; r++) { x0[r] = b2[f]; x1[r] = b2[128 + f]; x2[r] = b2[256 + f]; }
        for (int k = 0; k < 128; k++) {
            float w0 = W2[k * 384 + f];
            float w1 = W2[k * 384 + 128 + f];
            float w2 = W2[k * 384 + 256 + f];
#pragma unroll
            for (int r = 0; r < 4; r++) {
                float h = hs[2 * r + nb][k];
                x0[r] += h * w0; x1[r] += h * w1; x2[r] += h * w2;
            }
        }
#pragma unroll
        for (int r = 0; r < 4; r++) {
            int gn = n0 + 2 * r + nb;
            if (gn < N) {
                float* rec = P + (size_t)gn * 768 + f * 6;
                rec[0] = x0[r]; rec[1] = x1[r]; rec[2] = x2[r];
            }
        }
    }
}

// ---------------------------------------------------------------------------
// Edge aggregation: NPB nodes/block, CSR, no atomics. Per edge: 3x b64
// gathers from packed record P[j][f][0..6]; idx_j/row_ptr/geom made
// wave-uniform via readfirstlane so they take the scalar-memory path.
// Filter GEMV in packed fp32 from registers. Writes mu directly to muD.
__global__ __launch_bounds__(256) void k_edge(const float* __restrict__ P,
                                              const float* __restrict__ geom,
                                              const int* __restrict__ idx_j,
                                              const int* __restrict__ row_ptr,
                                              const float* __restrict__ filt_W,
                                              const float* __restrict__ filt_b,
                                              int layer,
                                              float* __restrict__ q,
                                              float* __restrict__ mu_out, int N) {
    __shared__ float red[4][128];
    int t = threadIdx.x;
    int f = t & 127, sub = t >> 7;

    v2f W0p[N_RBF / 2], W1p[N_RBF / 2], W2p[N_RBF / 2];
    const float* Wbase = filt_W + layer * 384;
#pragma unroll
    for (int j = 0; j < N_RBF / 2; j++) {
        W0p[j] = (v2f){Wbase[(2 * j) * 1152 + f],       Wbase[(2 * j + 1) * 1152 + f]};
        W1p[j] = (v2f){Wbase[(2 * j) * 1152 + 128 + f], Wbase[(2 * j + 1) * 1152 + 128 + f]};
        W2p[j] = (v2f){Wbase[(2 * j) * 1152 + 256 + f], Wbase[(2 * j + 1) * 1152 + 256 + f]};
    }
    float bf0 = filt_b[layer * 384 + f];
    float bf1 = filt_b[layer * 384 + 128 + f];
    float bf2 = filt_b[layer * 384 + 256 + f];

    int i0 = blockIdx.x * NPB;
    for (int nn = 0; nn < NPB; nn++) {
        int i = i0 + nn;
        if (i >= N) break;                       // uniform across block
        int rs = __builtin_amdgcn_readfirstlane(row_ptr[i]);
        int re = __builtin_amdgcn_readfirstlane(row_ptr[i + 1]);
        float dq = 0.f;
        v2f dm01 = (v2f){0.f, 0.f};
        float dm2 = 0.f;

        for (int e = rs + sub; e < re; e += 2) {
            int j = __builtin_amdgcn_readfirstlane(idx_j[e]);
            const float* rec = P + (size_t)j * 768 + f * 6;
            v2f ra = *(const v2f*)rec;        // xq, xr
            v2f rb = *(const v2f*)(rec + 2);  // xm, m0
            v2f rc = *(const v2f*)(rec + 4);  // m1, m2

            const float4* g4 = (const float4*)(geom + (size_t)e * 24);
            float4 a  = g4[0];                   // dirx, diry, dirz, fcut
            float4 p0 = g4[1], p1 = g4[2], p2 = g4[3], p3 = g4[4], p4 = g4[5];

            v2f ph[N_RBF / 2] = {
                (v2f){p0.x, p0.y}, (v2f){p0.z, p0.w},
                (v2f){p1.x, p1.y}, (v2f){p1.z, p1.w},
                (v2f){p2.x, p2.y}, (v2f){p2.z, p2.w},
                (v2f){p3.x, p3.y}, (v2f){p3.z, p3.w},
                (v2f){p4.x, p4.y}, (v2f){p4.z, p4.w}};
            v2f aq = (v2f){0.f, 0.f}, ar = (v2f){0.f, 0.f}, am = (v2f){0.f, 0.f};
#pragma unroll
            for (int k = 0; k < N_RBF / 2; k++) {
                aq += ph[k] * W0p[k];
                ar += ph[k] * W1p[k];
                am += ph[k] * W2p[k];
            }
            float wq = aq.x + aq.y + a.w * bf0;
            float wr = ar.x + ar.y + a.w * bf1;
            float wm = am.x + am.y + a.w * bf2;

            dq += wq * ra.x;
            float s_r = wr * ra.y, s_m = wm * rb.x;
            dm01 += (v2f){s_r, s_r} * (v2f){a.x, a.y} + (v2f){s_m, s_m} * (v2f){rb.y, rc.x};
            dm2  += s_r * a.z + s_m * rc.y;
        }

        if (sub == 1) { red[0][f] = dq; red[1][f] = dm01.x; red[2][f] = dm01.y; red[3][f] = dm2; }
        __syncthreads();
        if (sub == 0) {
            const float* reci = P + (size_t)i * 768 + f * 6;   // own node's mu
            dq += red[0][f];
            float d0 = dm01.x + red[1][f], d1 = dm01.y + red[2][f];
            dm2 += red[3][f];
            q[(size_t)i * 128 + f] += dq;
            size_t base = (size_t)i * 384;
            mu_out[base + f]       = reci[3] + d0;
            mu_out[base + 128 + f] = reci[4] + d1;
            mu_out[base + 256 + f] = reci[5] + dm2;
        }
        __syncthreads();
    }
}

// ---------------------------------------------------------------------------
// Mixing block: 4 nodes/block (2500 blocks for TLP). Updates q and mu
// (in muD) in place and writes the mu-part of P records: P[n][f][3..5].
__global__ __launch_bounds__(256) void k_mix(float* __restrict__ q,
                                             float* __restrict__ mu,
                                             const float* __restrict__ muxW,
                                             const float* __restrict__ W1,
                                             const float* __restrict__ b1,
                                             const float* __restrict__ W2,
                                             const float* __restrict__ b2,
                                             float* __restrict__ P, int N) {
    __shared__ float mus[4][3][128];
    __shared__ float qs[4][128];
    __shared__ float Vs[4][3][128];
    __shared__ float Ws_[4][3][128];
    __shared__ float vns[4][128];
    __shared__ float hs[4][128];
    int n0 = blockIdx.x * 4;
    int t = threadIdx.x;
    int f = t & 127, nb = t >> 7;

    for (int idx = t; idx < 1536; idx += 256) {
        int n = idx / 384, rem = idx % 384;
        int gn = n0 + n;
        ((float*)mus)[idx] = (gn < N) ? mu[(size_t)gn * 384 + rem] : 0.f;
    }
    for (int idx = t; idx < 512; idx += 256) {
        int n = idx >> 7, ff = idx & 127;
        int gn = n0 + n;
        qs[n][ff] = (gn < N) ? q[(size_t)gn * 128 + ff] : 0.f;
    }
    __syncthreads();

    {   // mu_mix = mu @ muxW : nb==0 computes V cols, nb==1 the W cols
        float acc[4][3];
#pragma unroll
        for (int n = 0; n < 4; n++)
#pragma unroll
            for (int c = 0; c < 3; c++) acc[n][c] = 0.f;
        for (int k = 0; k < 128; k++) {
            float w = muxW[k * 256 + nb * 128 + f];
#pragma unroll
            for (int n = 0; n < 4; n++) {
                acc[n][0] += mus[n][0][k] * w;
                acc[n][1] += mus[n][1][k] * w;
                acc[n][2] += mus[n][2][k] * w;
            }
        }
        if (nb == 0) {
#pragma unroll
            for (int n = 0; n < 4; n++)
#pragma unroll
                for (int c = 0; c < 3; c++) Vs[n][c][f] = acc[n][c];
        } else {
#pragma unroll
            for (int n = 0; n < 4; n++)
#pragma unroll
                for (int c = 0; c < 3; c++) Ws_[n][c][f] = acc[n][c];
        }
    }
    __syncthreads();

    for (int idx = t; idx < 512; idx += 256) {
        int n = idx >> 7, ff = idx & 127;
        float v0 = Vs[n][0][ff], v1 = Vs[n][1][ff], v2 = Vs[n][2][ff];
        vns[n][ff] = sqrtf(v0 * v0 + v1 * v1 + v2 * v2 + 1e-8f);
    }
    __syncthreads();

    {   // h = silu([q, vn] @ W1 + b1)
        float acc[2];
#pragma unroll
        for (int r = 0; r < 2; r++) acc[r] = b1[f];
        for (int k = 0; k < 128; k++) {
            float w = W1[k * 128 + f];
#pragma unroll
            for (int r = 0; r < 2; r++) acc[r] += qs[2 * r + nb][k] * w;
        }
        for (int k = 0; k < 128; k++) {
            float w = W1[(128 + k) * 128 + f];
#pragma unroll
            for (int r = 0; r < 2; r++) acc[r] += vns[2 * r + nb][k] * w;
        }
#pragma unroll
        for (int r = 0; r < 2; r++) {
            float a = acc[r];
            hs[2 * r + nb][f] = a / (1.f + __expf(-a));
        }
    }
    __syncthreads();

    {   // x = h @ W2 + b2 ; then update q, mu, P
        float x0[2], x1[2], x2[2];
#pragma unroll
        for (int r = 0; r < 2; r++) { x0[r] = b2[f]; x1[r] = b2[128 + f]; x2[r] = b2[256 + f]; }
        for (int k = 0; k < 128; k++) {
            float w0 = W2[k * 384 + f];
            float w1 = W2[k * 384 + 128 + f];
            float w2 = W2[k * 384 + 256 + f];
#pragma unroll
            for (int r = 0; r < 2; r++) {
                float h = hs[2 * r + nb][k];
                x0[r] += h * w0; x1[r] += h * w1; x2[r] += h * w2;
            }
        }
#pragma unroll
        for (int r = 0; r < 2; r++) {
            int n = 2 * r + nb;
            int gn = n0 + n;
            if (gn >= N) continue;
            float S = Vs[n][0][f] * Ws_[n][0][f] + Vs[n][1][f] * Ws_[n][1][f] +
                      Vs[n][2][f] * Ws_[n][2][f];
            q[(size_t)gn * 128 + f] = qs[n][f] + x0[r] + x2[r] * S;
            size_t base = (size_t)gn * 384;
            float* rec = P + (size_t)gn * 768 + f * 6;
#pragma unroll
            for (int c = 0; c < 3; c++) {
                float m = mus[n][c][f] + x1[r] * Ws_[n][c][f];
                mu[base + c * 128 + f] = m;
                rec[3 + c] = m;
            }
        }
    }
}

// ---------------------------------------------------------------------------
extern "C" void kernel_launch(void* const* d_in, const int* in_sizes, int n_in,
                              void* d_out, int out_size, void* d_ws, size_t ws_size,
                              hipStream_t stream) {
    const int*   Z      = (const int*)d_in[0];
    const float* r_ij   = (const float*)d_in[1];
    const int*   idx_i  = (const int*)d_in[2];
    const int*   idx_j  = (const int*)d_in[3];
    const float* emb    = (const float*)d_in[4];
    const float* filt_W = (const float*)d_in[5];
    const float* filt_b = (const float*)d_in[6];
    const float* int_W1 = (const float*)d_in[7];
    const float* int_b1 = (const float*)d_in[8];
    const float* int_W2 = (const float*)d_in[9];
    const float* int_b2 = (const float*)d_in[10];
    const float* mix_W1 = (const float*)d_in[11];
    const float* mix_b1 = (const float*)d_in[12];
    const float* mix_W2 = (const float*)d_in[13];
    const float* mix_b2 = (const float*)d_in[14];
    const float* mux_W  = (const float*)d_in[15];

    int N = in_sizes[0];
    int E = in_sizes[2];

    float* q   = (float*)d_out;              // [N,128]
    float* muD = q + (size_t)N * 128;        // [N,3,128] — working + final mu

    float* ws   = (float*)d_ws;
    float* geom = ws;                          // E*24
    float* P    = geom + (size_t)E * 24;       // N*768 packed records
    int* row_ptr = (int*)(P + (size_t)N * 768);  // N+1

    k_rowptr<<<(N + 1 + 255) / 256, 256, 0, stream>>>(idx_i, row_ptr, N, E);
    k_init<<<((size_t)N * 768 + 255) / 256, 256, 0, stream>>>(Z, emb, q, P, N);
    k_geom<<<(E + 255) / 256, 256, 0, stream>>>(r_ij, geom, E);

    for (int l = 0; l < 3; l++) {
        k_node_msg<<<(N + 7) / 8, 256, 0, stream>>>(
            q, int_W1 + (size_t)l * 128 * 128, int_b1 + l * 128,
            int_W2 + (size_t)l * 128 * 384, int_b2 + l * 384, P, N);
        k_edge<<<(N + NPB - 1) / NPB, 256, 0, stream>>>(
            P, geom, idx_j, row_ptr, filt_W, filt_b, l, q, muD, N);
        k_mix<<<(N + 3) / 4, 256, 0, stream>>>(
            q, muD, mux_W + (size_t)l * 128 * 256,
            mix_W1 + (size_t)l * 256 * 128, mix_b1 + l * 128,
            mix_W2 + (size_t)l * 128 * 384, mix_b2 + l * 384, P, N);
    }
    // q in d_out; final mu in muD (d_out mu region).
}

// Round 6
// 778.352 us; speedup vs baseline: 1.3825x; 1.3825x over previous
//
#include <hip/hip_runtime.h>
#include <hip/hip_bf16.h>

#define F_DIM 128
#define N_RBF 20
#define CUTOFF 5.0f
#define PI_F 3.14159265358979323846f
#define NPB 4   // nodes per k_edge block

typedef float v2f __attribute__((ext_vector_type(2)));

// bf16 helpers: RTNE pack, shift-unpack
__device__ __forceinline__ unsigned int bf16_rtne(float f) {
    unsigned int u = __float_as_uint(f);
    u += 0x7fffu + ((u >> 16) & 1u);
    return u >> 16;
}
__device__ __forceinline__ unsigned int pack_bf2(float lo, float hi) {
    return bf16_rtne(lo) | (bf16_rtne(hi) << 16);
}
__device__ __forceinline__ float unpk_lo(unsigned int u) {
    return __uint_as_float(u << 16);
}
__device__ __forceinline__ float unpk_hi(unsigned int u) {
    return __uint_as_float(u & 0xffff0000u);
}

// ---------------------------------------------------------------------------
__global__ __launch_bounds__(256) void k_rowptr(const int* __restrict__ idx_i,
                                                int* __restrict__ row_ptr, int N, int E) {
    int i = blockIdx.x * blockDim.x + threadIdx.x;
    if (i > N) return;
    if (i == N) { row_ptr[N] = E; return; }
    int lo = 0, hi = E;
    while (lo < hi) {
        int mid = (lo + hi) >> 1;
        if (idx_i[mid] < i) lo = mid + 1; else hi = mid;
    }
    row_ptr[i] = lo;
}

// ---------------------------------------------------------------------------
// q = embedding[Z]; P = 0 (bf16 message planes); muD = 0 (fp32 mu state)
__global__ __launch_bounds__(256) void k_init(const int* __restrict__ Z,
                                              const float* __restrict__ emb,
                                              float* __restrict__ q,
                                              unsigned int* __restrict__ P,
                                              float* __restrict__ muD, int N) {
    int idx = blockIdx.x * blockDim.x + threadIdx.x;
    if (idx < N * F_DIM) {
        int n = idx >> 7, f = idx & 127;
        q[idx] = emb[Z[n] * F_DIM + f];
    }
    if (idx < N * 384) { P[idx] = 0u; muD[idx] = 0.f; }
}

// ---------------------------------------------------------------------------
__global__ __launch_bounds__(256) void k_geom(const float* __restrict__ r,
                                              float* __restrict__ geom, int E) {
    int e = blockIdx.x * blockDim.x + threadIdx.x;
    if (e >= E) return;
    float x = r[e * 3], y = r[e * 3 + 1], z = r[e * 3 + 2];
    float d = sqrtf(x * x + y * y + z * z);
    float inv = 1.f / d;
    float fc = (d < CUTOFF) ? 0.5f * (__cosf(d * (PI_F / CUTOFF)) + 1.f) : 0.f;
    float* g = geom + (size_t)e * 24;
    g[0] = x * inv; g[1] = y * inv; g[2] = z * inv; g[3] = fc;
    const float delta = CUTOFF / (N_RBF - 1);
    const float coeff = -0.5f / (delta * delta);
#pragma unroll
    for (int k = 0; k < N_RBF; k++) {
        float t = d - k * delta;
        g[4 + k] = __expf(coeff * t * t) * fc;
    }
}

// ---------------------------------------------------------------------------
// x = silu(q@W1 + b1)@W2 + b2   8 nodes/block. Writes message planes:
// P[n*384+f] = (xq|xr),  lo16 of P[n*384+256+f] = xm.
__global__ __launch_bounds__(256) void k_node_msg(const float* __restrict__ q,
                                                  const float* __restrict__ W1,
                                                  const float* __restrict__ b1,
                                                  const float* __restrict__ W2,
                                                  const float* __restrict__ b2,
                                                  unsigned int* __restrict__ P, int N) {
    __shared__ float qs[8][128];
    __shared__ float hs[8][128];
    int n0 = blockIdx.x * 8;
    int t = threadIdx.x;
    int f = t & 127, nb = t >> 7;

    for (int r = 0; r < 4; r++) {
        int idx = r * 256 + t;
        int n = idx >> 7, ff = idx & 127;
        int gn = n0 + n;
        qs[n][ff] = (gn < N) ? q[(size_t)gn * 128 + ff] : 0.f;
    }
    __syncthreads();

    {   // h = silu(q@W1 + b1)
        float acc[4];
#pragma unroll
        for (int r = 0; r < 4; r++) acc[r] = b1[f];
        for (int k = 0; k < 128; k++) {
            float w = W1[k * 128 + f];
#pragma unroll
            for (int r = 0; r < 4; r++) acc[r] += qs[2 * r + nb][k] * w;
        }
#pragma unroll
        for (int r = 0; r < 4; r++) {
            float a = acc[r];
            hs[2 * r + nb][f] = a / (1.f + __expf(-a));
        }
    }
    __syncthreads();

    {   // x = h@W2 + b2  -> message planes
        float x0[4], x1[4], x2[4];
#pragma unroll
        for (int r = 0; r < 4; r++) { x0[r] = b2[f]; x1[r] = b2[128 + f]; x2[r] = b2[256 + f]; }
        for (int k = 0; k < 128; k++) {
            float w0 = W2[k * 384 + f];
            float w1 = W2[k * 384 + 128 + f];
            float w2 = W2[k * 384 + 256 + f];
#pragma unroll
            for (int r = 0; r < 4; r++) {
                float h = hs[2 * r + nb][k];
                x0[r] += h * w0; x1[r] += h * w1; x2[r] += h * w2;
            }
        }
#pragma unroll
        for (int r = 0; r < 4; r++) {
            int gn = n0 + 2 * r + nb;
            if (gn < N) {
                size_t base = (size_t)gn * 384;
                P[base + f] = pack_bf2(x0[r], x1[r]);
                ((unsigned short*)&P[base + 256 + f])[0] =
                    (unsigned short)bf16_rtne(x2[r]);      // lo half = xm
            }
        }
    }
}

// ---------------------------------------------------------------------------
// Edge aggregation: NPB nodes/block, CSR, no atomics. Per edge:
// 3 coalesced dword gathers of bf16-packed messages; idx_j/geom are
// wave-uniform (scalar path). mu state stays fp32 in muD (in-place +=).
__global__ __launch_bounds__(256) void k_edge(const unsigned int* __restrict__ P,
                                              const float* __restrict__ geom,
                                              const int* __restrict__ idx_j,
                                              const int* __restrict__ row_ptr,
                                              const float* __restrict__ filt_W,
                                              const float* __restrict__ filt_b,
                                              int layer,
                                              float* __restrict__ q,
                                              float* __restrict__ muD, int N) {
    __shared__ float red[4][128];
    int t = threadIdx.x;
    int f = t & 127;
    int sub = __builtin_amdgcn_readfirstlane(t >> 7);  // wave-uniform

    v2f W0p[N_RBF / 2], W1p[N_RBF / 2], W2p[N_RBF / 2];
    const float* Wbase = filt_W + layer * 384;
#pragma unroll
    for (int j = 0; j < N_RBF / 2; j++) {
        W0p[j] = (v2f){Wbase[(2 * j) * 1152 + f],       Wbase[(2 * j + 1) * 1152 + f]};
        W1p[j] = (v2f){Wbase[(2 * j) * 1152 + 128 + f], Wbase[(2 * j + 1) * 1152 + 128 + f]};
        W2p[j] = (v2f){Wbase[(2 * j) * 1152 + 256 + f], Wbase[(2 * j + 1) * 1152 + 256 + f]};
    }
    float bf0 = filt_b[layer * 384 + f];
    float bf1 = filt_b[layer * 384 + 128 + f];
    float bf2 = filt_b[layer * 384 + 256 + f];

    int i0 = blockIdx.x * NPB;
    for (int nn = 0; nn < NPB; nn++) {
        int i = i0 + nn;
        if (i >= N) break;                       // uniform across block
        int rs = __builtin_amdgcn_readfirstlane(row_ptr[i]);
        int re = __builtin_amdgcn_readfirstlane(row_ptr[i + 1]);
        float dq = 0.f;
        v2f dm01 = (v2f){0.f, 0.f};
        float dm2 = 0.f;

        for (int e = rs + sub; e < re; e += 2) {
            int j = __builtin_amdgcn_readfirstlane(idx_j[e]);
            const unsigned int* Pj = P + (size_t)j * 384;
            unsigned int A = Pj[f];          // (xq|xr)
            unsigned int B = Pj[128 + f];    // (m0|m1)
            unsigned int C = Pj[256 + f];    // (xm|m2)

            const float4* g4 = (const float4*)(geom + (size_t)e * 24);
            float4 a  = g4[0];               // dirx, diry, dirz, fcut
            float4 p0 = g4[1], p1 = g4[2], p2 = g4[3], p3 = g4[4], p4 = g4[5];

            v2f ph[N_RBF / 2] = {
                (v2f){p0.x, p0.y}, (v2f){p0.z, p0.w},
                (v2f){p1.x, p1.y}, (v2f){p1.z, p1.w},
                (v2f){p2.x, p2.y}, (v2f){p2.z, p2.w},
                (v2f){p3.x, p3.y}, (v2f){p3.z, p3.w},
                (v2f){p4.x, p4.y}, (v2f){p4.z, p4.w}};
            v2f aq = (v2f){0.f, 0.f}, ar = (v2f){0.f, 0.f}, am = (v2f){0.f, 0.f};
#pragma unroll
            for (int k = 0; k < N_RBF / 2; k++) {
                aq += ph[k] * W0p[k];
                ar += ph[k] * W1p[k];
                am += ph[k] * W2p[k];
            }
            float wq = aq.x + aq.y + a.w * bf0;
            float wr = ar.x + ar.y + a.w * bf1;
            float wm = am.x + am.y + a.w * bf2;

            float xq = unpk_lo(A), xr = unpk_hi(A);
            float m0 = unpk_lo(B), m1 = unpk_hi(B);
            float xm = unpk_lo(C), m2 = unpk_hi(C);

            dq += wq * xq;
            float s_r = wr * xr, s_m = wm * xm;
            dm01 += (v2f){s_r, s_r} * (v2f){a.x, a.y} + (v2f){s_m, s_m} * (v2f){m0, m1};
            dm2  += s_r * a.z + s_m * m2;
        }

        if (sub == 1) { red[0][f] = dq; red[1][f] = dm01.x; red[2][f] = dm01.y; red[3][f] = dm2; }
        __syncthreads();
        if (sub == 0) {
            dq += red[0][f];
            float d0 = dm01.x + red[1][f], d1 = dm01.y + red[2][f];
            dm2 += red[3][f];
            q[(size_t)i * 128 + f] += dq;
            size_t base = (size_t)i * 384;
            muD[base + f]       += d0;
            muD[base + 128 + f] += d1;
            muD[base + 256 + f] += dm2;
        }
        __syncthreads();
    }
}

// ---------------------------------------------------------------------------
// Mixing block: 4 nodes/block. Updates q and muD (fp32 state) in place and
// writes bf16 mu-message planes: P[n*384+128+f]=(m0|m1), hi16 of plane2=m2.
__global__ __launch_bounds__(256) void k_mix(float* __restrict__ q,
                                             float* __restrict__ mu,
                                             const float* __restrict__ muxW,
                                             const float* __restrict__ W1,
                                             const float* __restrict__ b1,
                                             const float* __restrict__ W2,
                                             const float* __restrict__ b2,
                                             unsigned int* __restrict__ P, int N) {
    __shared__ float mus[4][3][128];
    __shared__ float qs[4][128];
    __shared__ float Vs[4][3][128];
    __shared__ float Ws_[4][3][128];
    __shared__ float vns[4][128];
    __shared__ float hs[4][128];
    int n0 = blockIdx.x * 4;
    int t = threadIdx.x;
    int f = t & 127, nb = t >> 7;

    for (int idx = t; idx < 1536; idx += 256) {
        int n = idx / 384, rem = idx % 384;
        int gn = n0 + n;
        ((float*)mus)[idx] = (gn < N) ? mu[(size_t)gn * 384 + rem] : 0.f;
    }
    for (int idx = t; idx < 512; idx += 256) {
        int n = idx >> 7, ff = idx & 127;
        int gn = n0 + n;
        qs[n][ff] = (gn < N) ? q[(size_t)gn * 128 + ff] : 0.f;
    }
    __syncthreads();

    {   // mu_mix = mu @ muxW : nb==0 computes V cols, nb==1 the W cols
        float acc[4][3];
#pragma unroll
        for (int n = 0; n < 4; n++)
#pragma unroll
            for (int c = 0; c < 3; c++) acc[n][c] = 0.f;
        for (int k = 0; k < 128; k++) {
            float w = muxW[k * 256 + nb * 128 + f];
#pragma unroll
            for (int n = 0; n < 4; n++) {
                acc[n][0] += mus[n][0][k] * w;
                acc[n][1] += mus[n][1][k] * w;
                acc[n][2] += mus[n][2][k] * w;
            }
        }
        if (nb == 0) {
#pragma unroll
            for (int n = 0; n < 4; n++)
#pragma unroll
                for (int c = 0; c < 3; c++) Vs[n][c][f] = acc[n][c];
        } else {
#pragma unroll
            for (int n = 0; n < 4; n++)
#pragma unroll
                for (int c = 0; c < 3; c++) Ws_[n][c][f] = acc[n][c];
        }
    }
    __syncthreads();

    for (int idx = t; idx < 512; idx += 256) {
        int n = idx >> 7, ff = idx & 127;
        float v0 = Vs[n][0][ff], v1 = Vs[n][1][ff], v2 = Vs[n][2][ff];
        vns[n][ff] = sqrtf(v0 * v0 + v1 * v1 + v2 * v2 + 1e-8f);
    }
    __syncthreads();

    {   // h = silu([q, vn] @ W1 + b1)
        float acc[2];
#pragma unroll
        for (int r = 0; r < 2; r++) acc[r] = b1[f];
        for (int k = 0; k < 128; k++) {
            float w = W1[k * 128 + f];
#pragma unroll
            for (int r = 0; r < 2; r++) acc[r] += qs[2 * r + nb][k] * w;
        }
        for (int k = 0; k < 128; k++) {
            float w = W1[(128 + k) * 128 + f];
#pragma unroll
            for (int r = 0; r < 2; r++) acc[r] += vns[2 * r + nb][k] * w;
        }
#pragma unroll
        for (int r = 0; r < 2; r++) {
            float a = acc[r];
            hs[2 * r + nb][f] = a / (1.f + __expf(-a));
        }
    }
    __syncthreads();

    {   // x = h @ W2 + b2 ; then update q, mu, P
        float x0[2], x1[2], x2[2];
#pragma unroll
        for (int r = 0; r < 2; r++) { x0[r] = b2[f]; x1[r] = b2[128 + f]; x2[r] = b2[256 + f]; }
        for (int k = 0; k < 128; k++) {
            float w0 = W2[k * 384 + f];
            float w1 = W2[k * 384 + 128 + f];
            float w2 = W2[k * 384 + 256 + f];
#pragma unroll
            for (int r = 0; r < 2; r++) {
                float h = hs[2 * r + nb][k];
                x0[r] += h * w0; x1[r] += h * w1; x2[r] += h * w2;
            }
        }
#pragma unroll
        for (int r = 0; r < 2; r++) {
            int n = 2 * r + nb;
            int gn = n0 + n;
            if (gn >= N) continue;
            float S = Vs[n][0][f] * Ws_[n][0][f] + Vs[n][1][f] * Ws_[n][1][f] +
                      Vs[n][2][f] * Ws_[n][2][f];
            q[(size_t)gn * 128 + f] = qs[n][f] + x0[r] + x2[r] * S;
            size_t base = (size_t)gn * 384;
            float m[3];
#pragma unroll
            for (int c = 0; c < 3; c++) {
                m[c] = mus[n][c][f] + x1[r] * Ws_[n][c][f];
                mu[base + c * 128 + f] = m[c];
            }
            P[base + 128 + f] = pack_bf2(m[0], m[1]);
            ((unsigned short*)&P[base + 256 + f])[1] =
                (unsigned short)bf16_rtne(m[2]);           // hi half = m2
        }
    }
}

// ---------------------------------------------------------------------------
extern "C" void kernel_launch(void* const* d_in, const int* in_sizes, int n_in,
                              void* d_out, int out_size, void* d_ws, size_t ws_size,
                              hipStream_t stream) {
    const int*   Z      = (const int*)d_in[0];
    const float* r_ij   = (const float*)d_in[1];
    const int*   idx_i  = (const int*)d_in[2];
    const int*   idx_j  = (const int*)d_in[3];
    const float* emb    = (const float*)d_in[4];
    const float* filt_W = (const float*)d_in[5];
    const float* filt_b = (const float*)d_in[6];
    const float* int_W1 = (const float*)d_in[7];
    const float* int_b1 = (const float*)d_in[8];
    const float* int_W2 = (const float*)d_in[9];
    const float* int_b2 = (const float*)d_in[10];
    const float* mix_W1 = (const float*)d_in[11];
    const float* mix_b1 = (const float*)d_in[12];
    const float* mix_W2 = (const float*)d_in[13];
    const float* mix_b2 = (const float*)d_in[14];
    const float* mux_W  = (const float*)d_in[15];

    int N = in_sizes[0];
    int E = in_sizes[2];

    float* q   = (float*)d_out;              // [N,128]  q state (fp32)
    float* muD = q + (size_t)N * 128;        // [N,3,128] mu state (fp32)

    float* ws   = (float*)d_ws;
    float* geom = ws;                            // E*24 fp32
    unsigned int* P = (unsigned int*)(geom + (size_t)E * 24);  // N*384 u32 (bf16 pairs)
    int* row_ptr = (int*)(P + (size_t)N * 384);  // N+1

    k_rowptr<<<(N + 1 + 255) / 256, 256, 0, stream>>>(idx_i, row_ptr, N, E);
    k_init<<<((size_t)N * 384 + 255) / 256, 256, 0, stream>>>(Z, emb, q, P, muD, N);
    k_geom<<<(E + 255) / 256, 256, 0, stream>>>(r_ij, geom, E);

    for (int l = 0; l < 3; l++) {
        k_node_msg<<<(N + 7) / 8, 256, 0, stream>>>(
            q, int_W1 + (size_t)l * 128 * 128, int_b1 + l * 128,
            int_W2 + (size_t)l * 128 * 384, int_b2 + l * 384, P, N);
        k_edge<<<(N + NPB - 1) / NPB, 256, 0, stream>>>(
            P, geom, idx_j, row_ptr, filt_W, filt_b, l, q, muD, N);
        k_mix<<<(N + 3) / 4, 256, 0, stream>>>(
            q, muD, mux_W + (size_t)l * 128 * 256,
            mix_W1 + (size_t)l * 256 * 128, mix_b1 + l * 128,
            mix_W2 + (size_t)l * 128 * 384, mix_b2 + l * 384, P, N);
    }
    // q in d_out; final mu (fp32 state) in muD = d_out mu region.
}

// Round 7
// 657.273 us; speedup vs baseline: 1.6372x; 1.1842x over previous
//
#include <hip/hip_runtime.h>
#include <hip/hip_bf16.h>

#define F_DIM 128
#define N_RBF 20
#define CUTOFF 5.0f
#define PI_F 3.14159265358979323846f
#define NPB 4   // nodes per k_edge block

typedef float v2f __attribute__((ext_vector_type(2)));
typedef __attribute__((ext_vector_type(8))) short bf16x8;
typedef __attribute__((ext_vector_type(4))) float f32x4;

// bf16 helpers: RTNE pack, shift-unpack
__device__ __forceinline__ unsigned int bf16_rtne(float f) {
    unsigned int u = __float_as_uint(f);
    u += 0x7fffu + ((u >> 16) & 1u);
    return u >> 16;
}
__device__ __forceinline__ unsigned int pack_bf2(float lo, float hi) {
    return bf16_rtne(lo) | (bf16_rtne(hi) << 16);
}
__device__ __forceinline__ float unpk_lo(unsigned int u) {
    return __uint_as_float(u << 16);
}
__device__ __forceinline__ float unpk_hi(unsigned int u) {
    return __uint_as_float(u & 0xffff0000u);
}
__device__ __forceinline__ float bf16_to_f(unsigned short s) {
    return __uint_as_float(((unsigned int)s) << 16);
}

// ---------------------------------------------------------------------------
__global__ __launch_bounds__(256) void k_rowptr(const int* __restrict__ idx_i,
                                                int* __restrict__ row_ptr, int N, int E) {
    int i = blockIdx.x * blockDim.x + threadIdx.x;
    if (i > N) return;
    if (i == N) { row_ptr[N] = E; return; }
    int lo = 0, hi = E;
    while (lo < hi) {
        int mid = (lo + hi) >> 1;
        if (idx_i[mid] < i) lo = mid + 1; else hi = mid;
    }
    row_ptr[i] = lo;
}

// ---------------------------------------------------------------------------
// q = embedding[Z]; P = 0 (bf16 message planes); muD = 0 (fp32 mu state)
__global__ __launch_bounds__(256) void k_init(const int* __restrict__ Z,
                                              const float* __restrict__ emb,
                                              float* __restrict__ q,
                                              unsigned int* __restrict__ P,
                                              float* __restrict__ muD, int N) {
    int idx = blockIdx.x * blockDim.x + threadIdx.x;
    if (idx < N * F_DIM) {
        int n = idx >> 7, f = idx & 127;
        q[idx] = emb[Z[n] * F_DIM + f];
    }
    if (idx < N * 384) { P[idx] = 0u; muD[idx] = 0.f; }
}

// ---------------------------------------------------------------------------
// Transpose + bf16-convert node-MLP weights for MFMA B-operand (Bt[c][k]).
__global__ __launch_bounds__(256) void k_prep(const float* __restrict__ muxW,
                                              const float* __restrict__ W1,
                                              const float* __restrict__ W2,
                                              unsigned short* __restrict__ muxWt,
                                              unsigned short* __restrict__ W1t,
                                              unsigned short* __restrict__ W2t) {
    int idx = blockIdx.x * 256 + threadIdx.x;
    if (idx < 98304) {                     // muxWt[l][c<256][k<128]
        int l = idx / 32768, rem = idx % 32768;
        int c = rem / 128, k = rem % 128;
        muxWt[idx] = (unsigned short)bf16_rtne(muxW[l * 32768 + k * 256 + c]);
    } else if (idx < 196608) {             // W1t[l][c<128][k<256]
        int i2 = idx - 98304;
        int l = i2 / 32768, rem = i2 % 32768;
        int c = rem / 256, k = rem % 256;
        W1t[i2] = (unsigned short)bf16_rtne(W1[l * 32768 + k * 128 + c]);
    } else if (idx < 344064) {             // W2t[l][c<384][k<128]
        int i2 = idx - 196608;
        int l = i2 / 49152, rem = i2 % 49152;
        int c = rem / 128, k = rem % 128;
        W2t[i2] = (unsigned short)bf16_rtne(W2[l * 49152 + k * 384 + c]);
    }
}

// ---------------------------------------------------------------------------
__global__ __launch_bounds__(256) void k_geom(const float* __restrict__ r,
                                              float* __restrict__ geom, int E) {
    int e = blockIdx.x * blockDim.x + threadIdx.x;
    if (e >= E) return;
    float x = r[e * 3], y = r[e * 3 + 1], z = r[e * 3 + 2];
    float d = sqrtf(x * x + y * y + z * z);
    float inv = 1.f / d;
    float fc = (d < CUTOFF) ? 0.5f * (__cosf(d * (PI_F / CUTOFF)) + 1.f) : 0.f;
    float* g = geom + (size_t)e * 24;
    g[0] = x * inv; g[1] = y * inv; g[2] = z * inv; g[3] = fc;
    const float delta = CUTOFF / (N_RBF - 1);
    const float coeff = -0.5f / (delta * delta);
#pragma unroll
    for (int k = 0; k < N_RBF; k++) {
        float t = d - k * delta;
        g[4 + k] = __expf(coeff * t * t) * fc;
    }
}

// ---------------------------------------------------------------------------
// x = silu(q@W1 + b1)@W2 + b2   8 nodes/block. Writes message planes:
// P[n*384+f] = (xq|xr),  lo16 of P[n*384+256+f] = xm.
__global__ __launch_bounds__(256) void k_node_msg(const float* __restrict__ q,
                                                  const float* __restrict__ W1,
                                                  const float* __restrict__ b1,
                                                  const float* __restrict__ W2,
                                                  const float* __restrict__ b2,
                                                  unsigned int* __restrict__ P, int N) {
    __shared__ float qs[8][128];
    __shared__ float hs[8][128];
    int n0 = blockIdx.x * 8;
    int t = threadIdx.x;
    int f = t & 127, nb = t >> 7;

    for (int r = 0; r < 4; r++) {
        int idx = r * 256 + t;
        int n = idx >> 7, ff = idx & 127;
        int gn = n0 + n;
        qs[n][ff] = (gn < N) ? q[(size_t)gn * 128 + ff] : 0.f;
    }
    __syncthreads();

    {   // h = silu(q@W1 + b1)
        float acc[4];
#pragma unroll
        for (int r = 0; r < 4; r++) acc[r] = b1[f];
        for (int k = 0; k < 128; k++) {
            float w = W1[k * 128 + f];
#pragma unroll
            for (int r = 0; r < 4; r++) acc[r] += qs[2 * r + nb][k] * w;
        }
#pragma unroll
        for (int r = 0; r < 4; r++) {
            float a = acc[r];
            hs[2 * r + nb][f] = a / (1.f + __expf(-a));
        }
    }
    __syncthreads();

    {   // x = h@W2 + b2  -> message planes
        float x0[4], x1[4], x2[4];
#pragma unroll
        for (int r = 0; r < 4; r++) { x0[r] = b2[f]; x1[r] = b2[128 + f]; x2[r] = b2[256 + f]; }
        for (int k = 0; k < 128; k++) {
            float w0 = W2[k * 384 + f];
            float w1 = W2[k * 384 + 128 + f];
            float w2 = W2[k * 384 + 256 + f];
#pragma unroll
            for (int r = 0; r < 4; r++) {
                float h = hs[2 * r + nb][k];
                x0[r] += h * w0; x1[r] += h * w1; x2[r] += h * w2;
            }
        }
#pragma unroll
        for (int r = 0; r < 4; r++) {
            int gn = n0 + 2 * r + nb;
            if (gn < N) {
                size_t base = (size_t)gn * 384;
                P[base + f] = pack_bf2(x0[r], x1[r]);
                ((unsigned short*)&P[base + 256 + f])[0] =
                    (unsigned short)bf16_rtne(x2[r]);      // lo half = xm
            }
        }
    }
}

// ---------------------------------------------------------------------------
// Edge aggregation (unchanged from R6): NPB nodes/block, CSR, bf16 message
// gathers (3 coalesced dwords/edge), uniform idx/geom on scalar path.
__global__ __launch_bounds__(256) void k_edge(const unsigned int* __restrict__ P,
                                              const float* __restrict__ geom,
                                              const int* __restrict__ idx_j,
                                              const int* __restrict__ row_ptr,
                                              const float* __restrict__ filt_W,
                                              const float* __restrict__ filt_b,
                                              int layer,
                                              float* __restrict__ q,
                                              float* __restrict__ muD, int N) {
    __shared__ float red[4][128];
    int t = threadIdx.x;
    int f = t & 127;
    int sub = __builtin_amdgcn_readfirstlane(t >> 7);  // wave-uniform

    v2f W0p[N_RBF / 2], W1p[N_RBF / 2], W2p[N_RBF / 2];
    const float* Wbase = filt_W + layer * 384;
#pragma unroll
    for (int j = 0; j < N_RBF / 2; j++) {
        W0p[j] = (v2f){Wbase[(2 * j) * 1152 + f],       Wbase[(2 * j + 1) * 1152 + f]};
        W1p[j] = (v2f){Wbase[(2 * j) * 1152 + 128 + f], Wbase[(2 * j + 1) * 1152 + 128 + f]};
        W2p[j] = (v2f){Wbase[(2 * j) * 1152 + 256 + f], Wbase[(2 * j + 1) * 1152 + 256 + f]};
    }
    float bf0 = filt_b[layer * 384 + f];
    float bf1 = filt_b[layer * 384 + 128 + f];
    float bf2 = filt_b[layer * 384 + 256 + f];

    int i0 = blockIdx.x * NPB;
    for (int nn = 0; nn < NPB; nn++) {
        int i = i0 + nn;
        if (i >= N) break;
        int rs = __builtin_amdgcn_readfirstlane(row_ptr[i]);
        int re = __builtin_amdgcn_readfirstlane(row_ptr[i + 1]);
        float dq = 0.f;
        v2f dm01 = (v2f){0.f, 0.f};
        float dm2 = 0.f;

        for (int e = rs + sub; e < re; e += 2) {
            int j = __builtin_amdgcn_readfirstlane(idx_j[e]);
            const unsigned int* Pj = P + (size_t)j * 384;
            unsigned int A = Pj[f];
            unsigned int B = Pj[128 + f];
            unsigned int C = Pj[256 + f];

            const float4* g4 = (const float4*)(geom + (size_t)e * 24);
            float4 a  = g4[0];
            float4 p0 = g4[1], p1 = g4[2], p2 = g4[3], p3 = g4[4], p4 = g4[5];

            v2f ph[N_RBF / 2] = {
                (v2f){p0.x, p0.y}, (v2f){p0.z, p0.w},
                (v2f){p1.x, p1.y}, (v2f){p1.z, p1.w},
                (v2f){p2.x, p2.y}, (v2f){p2.z, p2.w},
                (v2f){p3.x, p3.y}, (v2f){p3.z, p3.w},
                (v2f){p4.x, p4.y}, (v2f){p4.z, p4.w}};
            v2f aq = (v2f){0.f, 0.f}, ar = (v2f){0.f, 0.f}, am = (v2f){0.f, 0.f};
#pragma unroll
            for (int k = 0; k < N_RBF / 2; k++) {
                aq += ph[k] * W0p[k];
                ar += ph[k] * W1p[k];
                am += ph[k] * W2p[k];
            }
            float wq = aq.x + aq.y + a.w * bf0;
            float wr = ar.x + ar.y + a.w * bf1;
            float wm = am.x + am.y + a.w * bf2;

            float xq = unpk_lo(A), xr = unpk_hi(A);
            float m0 = unpk_lo(B), m1 = unpk_hi(B);
            float xm = unpk_lo(C), m2 = unpk_hi(C);

            dq += wq * xq;
            float s_r = wr * xr, s_m = wm * xm;
            dm01 += (v2f){s_r, s_r} * (v2f){a.x, a.y} + (v2f){s_m, s_m} * (v2f){m0, m1};
            dm2  += s_r * a.z + s_m * m2;
        }

        if (sub == 1) { red[0][f] = dq; red[1][f] = dm01.x; red[2][f] = dm01.y; red[3][f] = dm2; }
        __syncthreads();
        if (sub == 0) {
            dq += red[0][f];
            float d0 = dm01.x + red[1][f], d1 = dm01.y + red[2][f];
            dm2 += red[3][f];
            q[(size_t)i * 128 + f] += dq;
            size_t base = (size_t)i * 384;
            muD[base + f]       += d0;
            muD[base + 128 + f] += d1;
            muD[base + 256 + f] += dm2;
        }
        __syncthreads();
    }
}

// ---------------------------------------------------------------------------
// MFMA mixing kernel: 1 wave (64 threads) per 16 nodes. All three GEMMs
// via v_mfma_f32_16x16x32_bf16 (fp32 accum). Wave-private LDS, no barriers.
// Layouts (verified): A[m=lane&15][k=quad*8+j]; B[k=quad*8+j][n=lane&15];
// D: row=quad*4+reg, col=lane&15.
__global__ __launch_bounds__(64) void k_mix_mfma(
        float* __restrict__ q, float* __restrict__ mu,
        const unsigned short* __restrict__ muxWt,   // [256][128] bf16 (c,k)
        const unsigned short* __restrict__ W1t,     // [128][256]
        const unsigned short* __restrict__ W2t,     // [384][128]
        const float* __restrict__ b1,
        const float* __restrict__ b2,
        unsigned int* __restrict__ P, int N) {
    __shared__ unsigned short A[16 * 264];          // activations, pitch 264 bf16
    __shared__ unsigned short Wsp[3 * 16 * 136];    // mu_W spill, pitch 136 bf16
    int l = threadIdx.x & 63;
    int quad = l >> 4, c0 = l & 15;
    int n0 = blockIdx.x * 16;

    // ---- stage q (fp32 -> bf16) into A[:, 0:128]
    for (int i = 0; i < 16; i++) {
        int flat = i * 64 + l;
        int node = flat >> 6, cp = flat & 63;
        int gn = n0 + node;
        unsigned int v = 0u;
        if (gn < N) {
            const float* src = q + (size_t)gn * 128 + 2 * cp;
            v = pack_bf2(src[0], src[1]);
        }
        *(unsigned int*)&A[node * 264 + 2 * cp] = v;
    }

    // ---- mux GEMM per spatial c: V(cols 0:128), W(cols 128:256)
    f32x4 vn2[8], S[8];
#pragma unroll
    for (int j = 0; j < 8; j++) { vn2[j] = (f32x4){0,0,0,0}; S[j] = (f32x4){0,0,0,0}; }

    for (int c = 0; c < 3; c++) {
        for (int i = 0; i < 16; i++) {          // stage mu[:,c,:] into A[:,128:256]
            int flat = i * 64 + l;
            int node = flat >> 6, cp = flat & 63;
            int gn = n0 + node;
            unsigned int v = 0u;
            if (gn < N) {
                const float* src = mu + (size_t)gn * 384 + c * 128 + 2 * cp;
                v = pack_bf2(src[0], src[1]);
            }
            *(unsigned int*)&A[node * 264 + 128 + 2 * cp] = v;
        }
        bf16x8 af[4];
#pragma unroll
        for (int ks = 0; ks < 4; ks++)
            af[ks] = *(const bf16x8*)&A[c0 * 264 + 128 + ks * 32 + quad * 8];

        f32x4 Vacc[8];
#pragma unroll
        for (int j = 0; j < 8; j++) {
            f32x4 acc = (f32x4){0,0,0,0};
#pragma unroll
            for (int ks = 0; ks < 4; ks++) {
                bf16x8 b = *(const bf16x8*)&muxWt[(16 * j + c0) * 128 + ks * 32 + quad * 8];
                acc = __builtin_amdgcn_mfma_f32_16x16x32_bf16(af[ks], b, acc, 0, 0, 0);
            }
            Vacc[j] = acc;
        }
#pragma unroll
        for (int j = 0; j < 8; j++) {
            f32x4 acc = (f32x4){0,0,0,0};
#pragma unroll
            for (int ks = 0; ks < 4; ks++) {
                bf16x8 b = *(const bf16x8*)&muxWt[(16 * (j + 8) + c0) * 128 + ks * 32 + quad * 8];
                acc = __builtin_amdgcn_mfma_f32_16x16x32_bf16(af[ks], b, acc, 0, 0, 0);
            }
            vn2[j] += Vacc[j] * Vacc[j];
            S[j]   += Vacc[j] * acc;
#pragma unroll
            for (int r = 0; r < 4; r++)
                Wsp[c * 2176 + (quad * 4 + r) * 136 + 16 * j + c0] =
                    (unsigned short)bf16_rtne(acc[r]);
        }
    }
    // ---- vn = sqrt(sum V^2 + eps) -> A[:, 128:256] (bf16)
#pragma unroll
    for (int j = 0; j < 8; j++)
#pragma unroll
        for (int r = 0; r < 4; r++) {
            float vnv = sqrtf(vn2[j][r] + 1e-8f);
            A[(quad * 4 + r) * 264 + 128 + 16 * j + c0] = (unsigned short)bf16_rtne(vnv);
        }

    // ---- GEMM2: h = silu([q|vn] @ W1 + b1), K=256, out 16x128
    bf16x8 a2[8];
#pragma unroll
    for (int ks = 0; ks < 8; ks++)
        a2[ks] = *(const bf16x8*)&A[c0 * 264 + ks * 32 + quad * 8];
    f32x4 hacc[8];
#pragma unroll
    for (int j = 0; j < 8; j++) {
        float bb = b1[16 * j + c0];
        f32x4 acc = (f32x4){bb, bb, bb, bb};
#pragma unroll
        for (int ks = 0; ks < 8; ks++) {
            bf16x8 b = *(const bf16x8*)&W1t[(16 * j + c0) * 256 + ks * 32 + quad * 8];
            acc = __builtin_amdgcn_mfma_f32_16x16x32_bf16(a2[ks], b, acc, 0, 0, 0);
        }
        hacc[j] = acc;
    }
#pragma unroll
    for (int j = 0; j < 8; j++)
#pragma unroll
        for (int r = 0; r < 4; r++) {
            float aa = hacc[j][r];
            float hh = aa / (1.f + __expf(-aa));
            A[(quad * 4 + r) * 264 + 16 * j + c0] = (unsigned short)bf16_rtne(hh);
        }

    // ---- GEMM3: x = h @ W2 + b2, K=128, out 16x384
    bf16x8 a3[4];
#pragma unroll
    for (int ks = 0; ks < 4; ks++)
        a3[ks] = *(const bf16x8*)&A[c0 * 264 + ks * 32 + quad * 8];
    f32x4 X[24];
#pragma unroll
    for (int j = 0; j < 24; j++) {
        float bb = b2[16 * j + c0];
        f32x4 acc = (f32x4){bb, bb, bb, bb};
#pragma unroll
        for (int ks = 0; ks < 4; ks++) {
            bf16x8 b = *(const bf16x8*)&W2t[(16 * j + c0) * 128 + ks * 32 + quad * 8];
            acc = __builtin_amdgcn_mfma_f32_16x16x32_bf16(a3[ks], b, acc, 0, 0, 0);
        }
        X[j] = acc;
    }

    // ---- epilogue: q += x0 + x2*S;  mu += x1*W;  write message planes
#pragma unroll
    for (int j = 0; j < 8; j++) {
#pragma unroll
        for (int r = 0; r < 4; r++) {
            int row = quad * 4 + r;
            int gn = n0 + row;
            if (gn >= N) continue;
            int f = 16 * j + c0;
            float x0 = X[j][r], x1 = X[8 + j][r], x2 = X[16 + j][r];
            size_t qoff = (size_t)gn * 128 + f;
            q[qoff] = q[qoff] + x0 + x2 * S[j][r];
            size_t mb = (size_t)gn * 384;
            float m[3];
#pragma unroll
            for (int c = 0; c < 3; c++) {
                float Wv = bf16_to_f(Wsp[c * 2176 + row * 136 + f]);
                float mm = mu[mb + c * 128 + f] + x1 * Wv;
                mu[mb + c * 128 + f] = mm;
                m[c] = mm;
            }
            P[mb + 128 + f] = pack_bf2(m[0], m[1]);
            ((unsigned short*)&P[mb + 256 + f])[1] = (unsigned short)bf16_rtne(m[2]);
        }
    }
}

// ---------------------------------------------------------------------------
extern "C" void kernel_launch(void* const* d_in, const int* in_sizes, int n_in,
                              void* d_out, int out_size, void* d_ws, size_t ws_size,
                              hipStream_t stream) {
    const int*   Z      = (const int*)d_in[0];
    const float* r_ij   = (const float*)d_in[1];
    const int*   idx_i  = (const int*)d_in[2];
    const int*   idx_j  = (const int*)d_in[3];
    const float* emb    = (const float*)d_in[4];
    const float* filt_W = (const float*)d_in[5];
    const float* filt_b = (const float*)d_in[6];
    const float* int_W1 = (const float*)d_in[7];
    const float* int_b1 = (const float*)d_in[8];
    const float* int_W2 = (const float*)d_in[9];
    const float* int_b2 = (const float*)d_in[10];
    const float* mix_W1 = (const float*)d_in[11];
    const float* mix_b1 = (const float*)d_in[12];
    const float* mix_W2 = (const float*)d_in[13];
    const float* mix_b2 = (const float*)d_in[14];
    const float* mux_W  = (const float*)d_in[15];

    int N = in_sizes[0];
    int E = in_sizes[2];

    float* q   = (float*)d_out;              // [N,128]  q state (fp32)
    float* muD = q + (size_t)N * 128;        // [N,3,128] mu state (fp32)

    float* ws   = (float*)d_ws;
    float* geom = ws;                            // E*24 fp32
    unsigned int* P = (unsigned int*)(geom + (size_t)E * 24);  // N*384 u32
    int* row_ptr = (int*)(P + (size_t)N * 384);  // N+1
    // bf16 transposed weights, 16B-aligned
    uintptr_t waddr = (uintptr_t)(row_ptr + N + 1);
    waddr = (waddr + 15) & ~(uintptr_t)15;
    unsigned short* muxWt = (unsigned short*)waddr;   // 3*256*128
    unsigned short* W1t   = muxWt + 98304;            // 3*128*256
    unsigned short* W2t   = W1t + 98304;              // 3*384*128

    k_rowptr<<<(N + 1 + 255) / 256, 256, 0, stream>>>(idx_i, row_ptr, N, E);
    k_init<<<((size_t)N * 384 + 255) / 256, 256, 0, stream>>>(Z, emb, q, P, muD, N);
    k_geom<<<(E + 255) / 256, 256, 0, stream>>>(r_ij, geom, E);
    k_prep<<<1344, 256, 0, stream>>>(mux_W, mix_W1, mix_W2, muxWt, W1t, W2t);

    for (int l = 0; l < 3; l++) {
        k_node_msg<<<(N + 7) / 8, 256, 0, stream>>>(
            q, int_W1 + (size_t)l * 128 * 128, int_b1 + l * 128,
            int_W2 + (size_t)l * 128 * 384, int_b2 + l * 384, P, N);
        k_edge<<<(N + NPB - 1) / NPB, 256, 0, stream>>>(
            P, geom, idx_j, row_ptr, filt_W, filt_b, l, q, muD, N);
        k_mix_mfma<<<(N + 15) / 16, 64, 0, stream>>>(
            q, muD, muxWt + (size_t)l * 32768, W1t + (size_t)l * 32768,
            W2t + (size_t)l * 49152, mix_b1 + l * 128, mix_b2 + l * 384, P, N);
    }
    // q in d_out; final mu (fp32 state) in muD = d_out mu region.
}

// Round 8
// 599.509 us; speedup vs baseline: 1.7949x; 1.0964x over previous
//
#include <hip/hip_runtime.h>
#include <hip/hip_bf16.h>

#define F_DIM 128
#define N_RBF 20
#define CUTOFF 5.0f
#define PI_F 3.14159265358979323846f
#define NPB 4   // nodes per k_edge block

typedef float v2f __attribute__((ext_vector_type(2)));
typedef __attribute__((ext_vector_type(8))) short bf16x8;
typedef __attribute__((ext_vector_type(4))) float f32x4;

// bf16 helpers: RTNE pack, shift-unpack
__device__ __forceinline__ unsigned int bf16_rtne(float f) {
    unsigned int u = __float_as_uint(f);
    u += 0x7fffu + ((u >> 16) & 1u);
    return u >> 16;
}
__device__ __forceinline__ unsigned int pack_bf2(float lo, float hi) {
    return bf16_rtne(lo) | (bf16_rtne(hi) << 16);
}
__device__ __forceinline__ float unpk_lo(unsigned int u) {
    return __uint_as_float(u << 16);
}
__device__ __forceinline__ float unpk_hi(unsigned int u) {
    return __uint_as_float(u & 0xffff0000u);
}
__device__ __forceinline__ float bf16_to_f(unsigned short s) {
    return __uint_as_float(((unsigned int)s) << 16);
}

// ---------------------------------------------------------------------------
__global__ __launch_bounds__(256) void k_rowptr(const int* __restrict__ idx_i,
                                                int* __restrict__ row_ptr, int N, int E) {
    int i = blockIdx.x * blockDim.x + threadIdx.x;
    if (i > N) return;
    if (i == N) { row_ptr[N] = E; return; }
    int lo = 0, hi = E;
    while (lo < hi) {
        int mid = (lo + hi) >> 1;
        if (idx_i[mid] < i) lo = mid + 1; else hi = mid;
    }
    row_ptr[i] = lo;
}

// ---------------------------------------------------------------------------
// q = embedding[Z]; P = 0 (bf16 message planes); muD = 0 (fp32 mu state)
__global__ __launch_bounds__(256) void k_init(const int* __restrict__ Z,
                                              const float* __restrict__ emb,
                                              float* __restrict__ q,
                                              unsigned int* __restrict__ P,
                                              float* __restrict__ muD, int N) {
    int idx = blockIdx.x * blockDim.x + threadIdx.x;
    if (idx < N * F_DIM) {
        int n = idx >> 7, f = idx & 127;
        q[idx] = emb[Z[n] * F_DIM + f];
    }
    if (idx < N * 384) { P[idx] = 0u; muD[idx] = 0.f; }
}

// ---------------------------------------------------------------------------
// Transpose + bf16-convert all node-MLP weights for MFMA B-operand (Bt[c][k]).
__global__ __launch_bounds__(256) void k_prep(const float* __restrict__ muxW,
                                              const float* __restrict__ W1,
                                              const float* __restrict__ W2,
                                              const float* __restrict__ iW1,
                                              const float* __restrict__ iW2,
                                              unsigned short* __restrict__ muxWt,
                                              unsigned short* __restrict__ W1t,
                                              unsigned short* __restrict__ W2t,
                                              unsigned short* __restrict__ iW1t,
                                              unsigned short* __restrict__ iW2t) {
    int idx = blockIdx.x * 256 + threadIdx.x;
    if (idx < 98304) {                     // muxWt[l][c<256][k<128]
        int l = idx / 32768, rem = idx % 32768;
        int c = rem / 128, k = rem % 128;
        muxWt[idx] = (unsigned short)bf16_rtne(muxW[l * 32768 + k * 256 + c]);
    } else if (idx < 196608) {             // W1t[l][c<128][k<256]
        int i2 = idx - 98304;
        int l = i2 / 32768, rem = i2 % 32768;
        int c = rem / 256, k = rem % 256;
        W1t[i2] = (unsigned short)bf16_rtne(W1[l * 32768 + k * 128 + c]);
    } else if (idx < 344064) {             // W2t[l][c<384][k<128]
        int i2 = idx - 196608;
        int l = i2 / 49152, rem = i2 % 49152;
        int c = rem / 128, k = rem % 128;
        W2t[i2] = (unsigned short)bf16_rtne(W2[l * 49152 + k * 384 + c]);
    } else if (idx < 393216) {             // iW1t[l][c<128][k<128]
        int i2 = idx - 344064;
        int l = i2 / 16384, rem = i2 % 16384;
        int c = rem / 128, k = rem % 128;
        iW1t[i2] = (unsigned short)bf16_rtne(iW1[l * 16384 + k * 128 + c]);
    } else if (idx < 540672) {             // iW2t[l][c<384][k<128]
        int i2 = idx - 393216;
        int l = i2 / 49152, rem = i2 % 49152;
        int c = rem / 128, k = rem % 128;
        iW2t[i2] = (unsigned short)bf16_rtne(iW2[l * 49152 + k * 384 + c]);
    }
}

// ---------------------------------------------------------------------------
__global__ __launch_bounds__(256) void k_geom(const float* __restrict__ r,
                                              float* __restrict__ geom, int E) {
    int e = blockIdx.x * blockDim.x + threadIdx.x;
    if (e >= E) return;
    float x = r[e * 3], y = r[e * 3 + 1], z = r[e * 3 + 2];
    float d = sqrtf(x * x + y * y + z * z);
    float inv = 1.f / d;
    float fc = (d < CUTOFF) ? 0.5f * (__cosf(d * (PI_F / CUTOFF)) + 1.f) : 0.f;
    float* g = geom + (size_t)e * 24;
    g[0] = x * inv; g[1] = y * inv; g[2] = z * inv; g[3] = fc;
    const float delta = CUTOFF / (N_RBF - 1);
    const float coeff = -0.5f / (delta * delta);
#pragma unroll
    for (int k = 0; k < N_RBF; k++) {
        float t = d - k * delta;
        g[4 + k] = __expf(coeff * t * t) * fc;
    }
}

// ---------------------------------------------------------------------------
// Node message MLP via MFMA: 4 waves per 16-node tile, wave w owns output
// column quarter. x = silu(q@W1+b1)@W2+b2 -> bf16 message planes (coalesced
// epilogue through LDS transpose).
__global__ __launch_bounds__(256) void k_node_mfma(
        const float* __restrict__ q,
        const unsigned short* __restrict__ iW1t,   // [128][128] bf16 (c,k)
        const float* __restrict__ b1,
        const unsigned short* __restrict__ iW2t,   // [384][128]
        const float* __restrict__ b2,
        unsigned int* __restrict__ P, int N) {
    __shared__ unsigned short A[16 * 136];
    __shared__ unsigned short Ah[16 * 136];
    __shared__ float Xs[16 * 396];
    int t = threadIdx.x;
    int w = t >> 6, l = t & 63, quad = l >> 4, c0 = l & 15;
    int n0 = blockIdx.x * 16;

    // stage q (fp32->bf16) into A
#pragma unroll
    for (int i = 0; i < 4; i++) {
        int flat = i * 256 + t;
        int node = flat >> 6, cp = flat & 63;
        int gn = n0 + node;
        unsigned int v = 0u;
        if (gn < N) { const float* s = q + (size_t)gn * 128 + 2 * cp; v = pack_bf2(s[0], s[1]); }
        *(unsigned int*)&A[node * 136 + 2 * cp] = v;
    }
    __syncthreads();

    bf16x8 a1[4];
#pragma unroll
    for (int ks = 0; ks < 4; ks++)
        a1[ks] = *(const bf16x8*)&A[c0 * 136 + ks * 32 + quad * 8];
#pragma unroll
    for (int jj = 0; jj < 2; jj++) {
        int jg = 2 * w + jj;
        float bb = b1[16 * jg + c0];
        f32x4 acc = (f32x4){bb, bb, bb, bb};
#pragma unroll
        for (int ks = 0; ks < 4; ks++) {
            bf16x8 b = *(const bf16x8*)&iW1t[(16 * jg + c0) * 128 + ks * 32 + quad * 8];
            acc = __builtin_amdgcn_mfma_f32_16x16x32_bf16(a1[ks], b, acc, 0, 0, 0);
        }
#pragma unroll
        for (int r = 0; r < 4; r++) {
            float aa = acc[r];
            Ah[(quad * 4 + r) * 136 + 16 * jg + c0] =
                (unsigned short)bf16_rtne(aa / (1.f + __expf(-aa)));
        }
    }
    __syncthreads();

    bf16x8 a3[4];
#pragma unroll
    for (int ks = 0; ks < 4; ks++)
        a3[ks] = *(const bf16x8*)&Ah[c0 * 136 + ks * 32 + quad * 8];
#pragma unroll
    for (int jj = 0; jj < 6; jj++) {
        int jx = 6 * w + jj;
        float bb = b2[16 * jx + c0];
        f32x4 acc = (f32x4){bb, bb, bb, bb};
#pragma unroll
        for (int ks = 0; ks < 4; ks++) {
            bf16x8 b = *(const bf16x8*)&iW2t[(16 * jx + c0) * 128 + ks * 32 + quad * 8];
            acc = __builtin_amdgcn_mfma_f32_16x16x32_bf16(a3[ks], b, acc, 0, 0, 0);
        }
#pragma unroll
        for (int r = 0; r < 4; r++)
            Xs[(quad * 4 + r) * 396 + 16 * jx + c0] = acc[r];
    }
    __syncthreads();

    // coalesced epilogue: thread -> (node, 8 contiguous features)
    int n = t >> 4, fi = (t & 15) * 8;
    int gn = n0 + n;
    if (gn < N) {
        size_t base = (size_t)gn * 384;
        unsigned int d[8];
#pragma unroll
        for (int k = 0; k < 8; k++) {
            float x0 = Xs[n * 396 + fi + k];
            float x1 = Xs[n * 396 + 128 + fi + k];
            float x2 = Xs[n * 396 + 256 + fi + k];
            d[k] = pack_bf2(x0, x1);
            ((unsigned short*)&P[base + 256 + fi + k])[0] = (unsigned short)bf16_rtne(x2);
        }
        *(uint4*)&P[base + fi]     = make_uint4(d[0], d[1], d[2], d[3]);
        *(uint4*)&P[base + fi + 4] = make_uint4(d[4], d[5], d[6], d[7]);
    }
}

// ---------------------------------------------------------------------------
// Edge aggregation (unchanged from R6/R7).
__global__ __launch_bounds__(256) void k_edge(const unsigned int* __restrict__ P,
                                              const float* __restrict__ geom,
                                              const int* __restrict__ idx_j,
                                              const int* __restrict__ row_ptr,
                                              const float* __restrict__ filt_W,
                                              const float* __restrict__ filt_b,
                                              int layer,
                                              float* __restrict__ q,
                                              float* __restrict__ muD, int N) {
    __shared__ float red[4][128];
    int t = threadIdx.x;
    int f = t & 127;
    int sub = __builtin_amdgcn_readfirstlane(t >> 7);

    v2f W0p[N_RBF / 2], W1p[N_RBF / 2], W2p[N_RBF / 2];
    const float* Wbase = filt_W + layer * 384;
#pragma unroll
    for (int j = 0; j < N_RBF / 2; j++) {
        W0p[j] = (v2f){Wbase[(2 * j) * 1152 + f],       Wbase[(2 * j + 1) * 1152 + f]};
        W1p[j] = (v2f){Wbase[(2 * j) * 1152 + 128 + f], Wbase[(2 * j + 1) * 1152 + 128 + f]};
        W2p[j] = (v2f){Wbase[(2 * j) * 1152 + 256 + f], Wbase[(2 * j + 1) * 1152 + 256 + f]};
    }
    float bf0 = filt_b[layer * 384 + f];
    float bf1 = filt_b[layer * 384 + 128 + f];
    float bf2 = filt_b[layer * 384 + 256 + f];

    int i0 = blockIdx.x * NPB;
    for (int nn = 0; nn < NPB; nn++) {
        int i = i0 + nn;
        if (i >= N) break;
        int rs = __builtin_amdgcn_readfirstlane(row_ptr[i]);
        int re = __builtin_amdgcn_readfirstlane(row_ptr[i + 1]);
        float dq = 0.f;
        v2f dm01 = (v2f){0.f, 0.f};
        float dm2 = 0.f;

        for (int e = rs + sub; e < re; e += 2) {
            int j = __builtin_amdgcn_readfirstlane(idx_j[e]);
            const unsigned int* Pj = P + (size_t)j * 384;
            unsigned int A = Pj[f];
            unsigned int B = Pj[128 + f];
            unsigned int C = Pj[256 + f];

            const float4* g4 = (const float4*)(geom + (size_t)e * 24);
            float4 a  = g4[0];
            float4 p0 = g4[1], p1 = g4[2], p2 = g4[3], p3 = g4[4], p4 = g4[5];

            v2f ph[N_RBF / 2] = {
                (v2f){p0.x, p0.y}, (v2f){p0.z, p0.w},
                (v2f){p1.x, p1.y}, (v2f){p1.z, p1.w},
                (v2f){p2.x, p2.y}, (v2f){p2.z, p2.w},
                (v2f){p3.x, p3.y}, (v2f){p3.z, p3.w},
                (v2f){p4.x, p4.y}, (v2f){p4.z, p4.w}};
            v2f aq = (v2f){0.f, 0.f}, ar = (v2f){0.f, 0.f}, am = (v2f){0.f, 0.f};
#pragma unroll
            for (int k = 0; k < N_RBF / 2; k++) {
                aq += ph[k] * W0p[k];
                ar += ph[k] * W1p[k];
                am += ph[k] * W2p[k];
            }
            float wq = aq.x + aq.y + a.w * bf0;
            float wr = ar.x + ar.y + a.w * bf1;
            float wm = am.x + am.y + a.w * bf2;

            float xq = unpk_lo(A), xr = unpk_hi(A);
            float m0 = unpk_lo(B), m1 = unpk_hi(B);
            float xm = unpk_lo(C), m2 = unpk_hi(C);

            dq += wq * xq;
            float s_r = wr * xr, s_m = wm * xm;
            dm01 += (v2f){s_r, s_r} * (v2f){a.x, a.y} + (v2f){s_m, s_m} * (v2f){m0, m1};
            dm2  += s_r * a.z + s_m * m2;
        }

        if (sub == 1) { red[0][f] = dq; red[1][f] = dm01.x; red[2][f] = dm01.y; red[3][f] = dm2; }
        __syncthreads();
        if (sub == 0) {
            dq += red[0][f];
            float d0 = dm01.x + red[1][f], d1 = dm01.y + red[2][f];
            dm2 += red[3][f];
            q[(size_t)i * 128 + f] += dq;
            size_t base = (size_t)i * 384;
            muD[base + f]       += d0;
            muD[base + 128 + f] += d1;
            muD[base + 256 + f] += dm2;
        }
        __syncthreads();
    }
}

// ---------------------------------------------------------------------------
// MFMA mixing kernel v2: 4 waves per 16-node tile, wave w owns output column
// quarter. LDS-transposed coalesced epilogue updates q/mu and message planes.
__global__ __launch_bounds__(256) void k_mix_mfma(
        float* __restrict__ q, float* __restrict__ mu,
        const unsigned short* __restrict__ muxWt,   // [256][128] bf16 (c,k)
        const unsigned short* __restrict__ W1t,     // [128][256]
        const unsigned short* __restrict__ W2t,     // [384][128]
        const float* __restrict__ b1,
        const float* __restrict__ b2,
        unsigned int* __restrict__ P, int N) {
    __shared__ unsigned short A[16 * 264];          // [node][K=256+pad] bf16
    __shared__ unsigned short Ah[16 * 136];         // h
    __shared__ unsigned short Wsp[3 * 16 * 136];    // mu_W bf16
    __shared__ float Xs[16 * 396];                  // x fp32
    __shared__ float Ss[16 * 140];                  // S = sum V*W fp32
    int t = threadIdx.x;
    int w = t >> 6, l = t & 63, quad = l >> 4, c0 = l & 15;
    int n0 = blockIdx.x * 16;

    // stage q -> A[:,0:128]
#pragma unroll
    for (int i = 0; i < 4; i++) {
        int flat = i * 256 + t;
        int node = flat >> 6, cp = flat & 63;
        int gn = n0 + node;
        unsigned int v = 0u;
        if (gn < N) { const float* s = q + (size_t)gn * 128 + 2 * cp; v = pack_bf2(s[0], s[1]); }
        *(unsigned int*)&A[node * 264 + 2 * cp] = v;
    }

    f32x4 vn2[2], S[2];
#pragma unroll
    for (int jj = 0; jj < 2; jj++) { vn2[jj] = (f32x4){0,0,0,0}; S[jj] = (f32x4){0,0,0,0}; }

    for (int c = 0; c < 3; c++) {
        // stage mu[:,c,:] -> A[:,128:256]
#pragma unroll
        for (int i = 0; i < 4; i++) {
            int flat = i * 256 + t;
            int node = flat >> 6, cp = flat & 63;
            int gn = n0 + node;
            unsigned int v = 0u;
            if (gn < N) {
                const float* s = mu + (size_t)gn * 384 + c * 128 + 2 * cp;
                v = pack_bf2(s[0], s[1]);
            }
            *(unsigned int*)&A[node * 264 + 128 + 2 * cp] = v;
        }
        __syncthreads();
        bf16x8 af[4];
#pragma unroll
        for (int ks = 0; ks < 4; ks++)
            af[ks] = *(const bf16x8*)&A[c0 * 264 + 128 + ks * 32 + quad * 8];
#pragma unroll
        for (int jj = 0; jj < 2; jj++) {
            int jv = 2 * w + jj;
            f32x4 V = (f32x4){0,0,0,0}, Wm = (f32x4){0,0,0,0};
#pragma unroll
            for (int ks = 0; ks < 4; ks++) {
                bf16x8 bV = *(const bf16x8*)&muxWt[(16 * jv + c0) * 128 + ks * 32 + quad * 8];
                V = __builtin_amdgcn_mfma_f32_16x16x32_bf16(af[ks], bV, V, 0, 0, 0);
            }
#pragma unroll
            for (int ks = 0; ks < 4; ks++) {
                bf16x8 bW = *(const bf16x8*)&muxWt[(16 * (jv + 8) + c0) * 128 + ks * 32 + quad * 8];
                Wm = __builtin_amdgcn_mfma_f32_16x16x32_bf16(af[ks], bW, Wm, 0, 0, 0);
            }
            vn2[jj] += V * V;
            S[jj]   += V * Wm;
#pragma unroll
            for (int r = 0; r < 4; r++)
                Wsp[c * 2176 + (quad * 4 + r) * 136 + 16 * jv + c0] =
                    (unsigned short)bf16_rtne(Wm[r]);
        }
        __syncthreads();
    }

    // vn -> A[:,128:256]
#pragma unroll
    for (int jj = 0; jj < 2; jj++) {
        int jv = 2 * w + jj;
#pragma unroll
        for (int r = 0; r < 4; r++)
            A[(quad * 4 + r) * 264 + 128 + 16 * jv + c0] =
                (unsigned short)bf16_rtne(sqrtf(vn2[jj][r] + 1e-8f));
    }
    __syncthreads();

    // GEMM2: h = silu([q|vn]@W1 + b1), K=256
    bf16x8 a2[8];
#pragma unroll
    for (int ks = 0; ks < 8; ks++)
        a2[ks] = *(const bf16x8*)&A[c0 * 264 + ks * 32 + quad * 8];
#pragma unroll
    for (int jj = 0; jj < 2; jj++) {
        int jg = 2 * w + jj;
        float bb = b1[16 * jg + c0];
        f32x4 acc = (f32x4){bb, bb, bb, bb};
#pragma unroll
        for (int ks = 0; ks < 8; ks++) {
            bf16x8 b = *(const bf16x8*)&W1t[(16 * jg + c0) * 256 + ks * 32 + quad * 8];
            acc = __builtin_amdgcn_mfma_f32_16x16x32_bf16(a2[ks], b, acc, 0, 0, 0);
        }
#pragma unroll
        for (int r = 0; r < 4; r++) {
            float aa = acc[r];
            Ah[(quad * 4 + r) * 136 + 16 * jg + c0] =
                (unsigned short)bf16_rtne(aa / (1.f + __expf(-aa)));
        }
    }
    __syncthreads();

    // GEMM3: x = h@W2 + b2, K=128
    bf16x8 a3[4];
#pragma unroll
    for (int ks = 0; ks < 4; ks++)
        a3[ks] = *(const bf16x8*)&Ah[c0 * 136 + ks * 32 + quad * 8];
#pragma unroll
    for (int jj = 0; jj < 6; jj++) {
        int jx = 6 * w + jj;
        float bb = b2[16 * jx + c0];
        f32x4 acc = (f32x4){bb, bb, bb, bb};
#pragma unroll
        for (int ks = 0; ks < 4; ks++) {
            bf16x8 b = *(const bf16x8*)&W2t[(16 * jx + c0) * 128 + ks * 32 + quad * 8];
            acc = __builtin_amdgcn_mfma_f32_16x16x32_bf16(a3[ks], b, acc, 0, 0, 0);
        }
#pragma unroll
        for (int r = 0; r < 4; r++)
            Xs[(quad * 4 + r) * 396 + 16 * jx + c0] = acc[r];
    }
#pragma unroll
    for (int jj = 0; jj < 2; jj++) {
        int jv = 2 * w + jj;
#pragma unroll
        for (int r = 0; r < 4; r++)
            Ss[(quad * 4 + r) * 140 + 16 * jv + c0] = S[jj][r];
    }
    __syncthreads();

    // coalesced epilogue: thread -> (node, 8 contiguous features)
    int n = t >> 4, fi = (t & 15) * 8;
    int gn = n0 + n;
    if (gn < N) {
        float* qp = q + (size_t)gn * 128 + fi;
#pragma unroll
        for (int k = 0; k < 8; k++)
            qp[k] = qp[k] + Xs[n * 396 + fi + k] +
                    Xs[n * 396 + 256 + fi + k] * Ss[n * 140 + fi + k];
        size_t base = (size_t)gn * 384;
        float m[3][8];
#pragma unroll
        for (int c = 0; c < 3; c++) {
            float* mp = mu + base + c * 128 + fi;
#pragma unroll
            for (int k = 0; k < 8; k++) {
                m[c][k] = mp[k] + Xs[n * 396 + 128 + fi + k] *
                                  bf16_to_f(Wsp[c * 2176 + n * 136 + fi + k]);
                mp[k] = m[c][k];
            }
        }
        unsigned int d[8];
#pragma unroll
        for (int k = 0; k < 8; k++) {
            d[k] = pack_bf2(m[0][k], m[1][k]);
            ((unsigned short*)&P[base + 256 + fi + k])[1] = (unsigned short)bf16_rtne(m[2][k]);
        }
        *(uint4*)&P[base + 128 + fi]     = make_uint4(d[0], d[1], d[2], d[3]);
        *(uint4*)&P[base + 128 + fi + 4] = make_uint4(d[4], d[5], d[6], d[7]);
    }
}

// ---------------------------------------------------------------------------
extern "C" void kernel_launch(void* const* d_in, const int* in_sizes, int n_in,
                              void* d_out, int out_size, void* d_ws, size_t ws_size,
                              hipStream_t stream) {
    const int*   Z      = (const int*)d_in[0];
    const float* r_ij   = (const float*)d_in[1];
    const int*   idx_i  = (const int*)d_in[2];
    const int*   idx_j  = (const int*)d_in[3];
    const float* emb    = (const float*)d_in[4];
    const float* filt_W = (const float*)d_in[5];
    const float* filt_b = (const float*)d_in[6];
    const float* int_W1 = (const float*)d_in[7];
    const float* int_b1 = (const float*)d_in[8];
    const float* int_W2 = (const float*)d_in[9];
    const float* int_b2 = (const float*)d_in[10];
    const float* mix_W1 = (const float*)d_in[11];
    const float* mix_b1 = (const float*)d_in[12];
    const float* mix_W2 = (const float*)d_in[13];
    const float* mix_b2 = (const float*)d_in[14];
    const float* mux_W  = (const float*)d_in[15];

    int N = in_sizes[0];
    int E = in_sizes[2];

    float* q   = (float*)d_out;              // [N,128]  q state (fp32)
    float* muD = q + (size_t)N * 128;        // [N,3,128] mu state (fp32)

    float* ws   = (float*)d_ws;
    float* geom = ws;                            // E*24 fp32
    unsigned int* P = (unsigned int*)(geom + (size_t)E * 24);  // N*384 u32
    int* row_ptr = (int*)(P + (size_t)N * 384);  // N+1
    uintptr_t waddr = (uintptr_t)(row_ptr + N + 1);
    waddr = (waddr + 15) & ~(uintptr_t)15;
    unsigned short* muxWt = (unsigned short*)waddr;   // 3*256*128
    unsigned short* W1t   = muxWt + 98304;            // 3*128*256
    unsigned short* W2t   = W1t + 98304;              // 3*384*128
    unsigned short* iW1t  = W2t + 147456;             // 3*128*128
    unsigned short* iW2t  = iW1t + 49152;             // 3*384*128

    k_rowptr<<<(N + 1 + 255) / 256, 256, 0, stream>>>(idx_i, row_ptr, N, E);
    k_init<<<((size_t)N * 384 + 255) / 256, 256, 0, stream>>>(Z, emb, q, P, muD, N);
    k_geom<<<(E + 255) / 256, 256, 0, stream>>>(r_ij, geom, E);
    k_prep<<<2112, 256, 0, stream>>>(mux_W, mix_W1, mix_W2, int_W1, int_W2,
                                     muxWt, W1t, W2t, iW1t, iW2t);

    int tiles = (N + 15) / 16;
    for (int l = 0; l < 3; l++) {
        k_node_mfma<<<tiles, 256, 0, stream>>>(
            q, iW1t + (size_t)l * 16384, int_b1 + l * 128,
            iW2t + (size_t)l * 49152, int_b2 + l * 384, P, N);
        k_edge<<<(N + NPB - 1) / NPB, 256, 0, stream>>>(
            P, geom, idx_j, row_ptr, filt_W, filt_b, l, q, muD, N);
        k_mix_mfma<<<tiles, 256, 0, stream>>>(
            q, muD, muxWt + (size_t)l * 32768, W1t + (size_t)l * 32768,
            W2t + (size_t)l * 49152, mix_b1 + l * 128, mix_b2 + l * 384, P, N);
    }
    // q in d_out; final mu (fp32 state) in muD = d_out mu region.
}

// Round 9
// 585.352 us; speedup vs baseline: 1.8383x; 1.0242x over previous
//
#include <hip/hip_runtime.h>
#include <hip/hip_bf16.h>

#define F_DIM 128
#define N_RBF 20
#define CUTOFF 5.0f
#define PI_F 3.14159265358979323846f
#define NPB 4   // nodes per k_edge block

typedef float v2f __attribute__((ext_vector_type(2)));
typedef __attribute__((ext_vector_type(8))) short bf16x8;
typedef __attribute__((ext_vector_type(4))) float f32x4;

__device__ __forceinline__ unsigned int bf16_rtne(float f) {
    unsigned int u = __float_as_uint(f);
    u += 0x7fffu + ((u >> 16) & 1u);
    return u >> 16;
}
__device__ __forceinline__ unsigned int pack_bf2(float lo, float hi) {
    return bf16_rtne(lo) | (bf16_rtne(hi) << 16);
}
__device__ __forceinline__ float unpk_lo(unsigned int u) {
    return __uint_as_float(u << 16);
}
__device__ __forceinline__ float unpk_hi(unsigned int u) {
    return __uint_as_float(u & 0xffff0000u);
}
__device__ __forceinline__ float bf16_to_f(unsigned short s) {
    return __uint_as_float(((unsigned int)s) << 16);
}

// ---------------------------------------------------------------------------
__global__ __launch_bounds__(256) void k_rowptr(const int* __restrict__ idx_i,
                                                int* __restrict__ row_ptr, int N, int E) {
    int i = blockIdx.x * blockDim.x + threadIdx.x;
    if (i > N) return;
    if (i == N) { row_ptr[N] = E; return; }
    int lo = 0, hi = E;
    while (lo < hi) {
        int mid = (lo + hi) >> 1;
        if (idx_i[mid] < i) lo = mid + 1; else hi = mid;
    }
    row_ptr[i] = lo;
}

// ---------------------------------------------------------------------------
__global__ __launch_bounds__(256) void k_init(const int* __restrict__ Z,
                                              const float* __restrict__ emb,
                                              float* __restrict__ q,
                                              unsigned int* __restrict__ P,
                                              float* __restrict__ muD, int N) {
    int idx = blockIdx.x * blockDim.x + threadIdx.x;
    if (idx < N * F_DIM) {
        int n = idx >> 7, f = idx & 127;
        q[idx] = emb[Z[n] * F_DIM + f];
    }
    if (idx < N * 384) { P[idx] = 0u; muD[idx] = 0.f; }
}

// ---------------------------------------------------------------------------
__global__ __launch_bounds__(256) void k_prep(const float* __restrict__ muxW,
                                              const float* __restrict__ W1,
                                              const float* __restrict__ W2,
                                              const float* __restrict__ iW1,
                                              const float* __restrict__ iW2,
                                              unsigned short* __restrict__ muxWt,
                                              unsigned short* __restrict__ W1t,
                                              unsigned short* __restrict__ W2t,
                                              unsigned short* __restrict__ iW1t,
                                              unsigned short* __restrict__ iW2t) {
    int idx = blockIdx.x * 256 + threadIdx.x;
    if (idx < 98304) {                     // muxWt[l][c<256][k<128]
        int l = idx / 32768, rem = idx % 32768;
        int c = rem / 128, k = rem % 128;
        muxWt[idx] = (unsigned short)bf16_rtne(muxW[l * 32768 + k * 256 + c]);
    } else if (idx < 196608) {             // W1t[l][c<128][k<256]
        int i2 = idx - 98304;
        int l = i2 / 32768, rem = i2 % 32768;
        int c = rem / 256, k = rem % 256;
        W1t[i2] = (unsigned short)bf16_rtne(W1[l * 32768 + k * 128 + c]);
    } else if (idx < 344064) {             // W2t[l][c<384][k<128]
        int i2 = idx - 196608;
        int l = i2 / 49152, rem = i2 % 49152;
        int c = rem / 128, k = rem % 128;
        W2t[i2] = (unsigned short)bf16_rtne(W2[l * 49152 + k * 384 + c]);
    } else if (idx < 393216) {             // iW1t[l][c<128][k<128]
        int i2 = idx - 344064;
        int l = i2 / 16384, rem = i2 % 16384;
        int c = rem / 128, k = rem % 128;
        iW1t[i2] = (unsigned short)bf16_rtne(iW1[l * 16384 + k * 128 + c]);
    } else if (idx < 540672) {             // iW2t[l][c<384][k<128]
        int i2 = idx - 393216;
        int l = i2 / 49152, rem = i2 % 49152;
        int c = rem / 128, k = rem % 128;
        iW2t[i2] = (unsigned short)bf16_rtne(iW2[l * 49152 + k * 384 + c]);
    }
}

// ---------------------------------------------------------------------------
__global__ __launch_bounds__(256) void k_geom(const float* __restrict__ r,
                                              float* __restrict__ geom, int E) {
    int e = blockIdx.x * blockDim.x + threadIdx.x;
    if (e >= E) return;
    float x = r[e * 3], y = r[e * 3 + 1], z = r[e * 3 + 2];
    float d = sqrtf(x * x + y * y + z * z);
    float inv = 1.f / d;
    float fc = (d < CUTOFF) ? 0.5f * (__cosf(d * (PI_F / CUTOFF)) + 1.f) : 0.f;
    float* g = geom + (size_t)e * 24;
    g[0] = x * inv; g[1] = y * inv; g[2] = z * inv; g[3] = fc;
    const float delta = CUTOFF / (N_RBF - 1);
    const float coeff = -0.5f / (delta * delta);
#pragma unroll
    for (int k = 0; k < N_RBF; k++) {
        float t = d - k * delta;
        g[4 + k] = __expf(coeff * t * t) * fc;
    }
}

// ---------------------------------------------------------------------------
// Node message MLP via MFMA (used for layer 0 only; later layers fused into
// k_mix_fused). 4 waves per 16-node tile.
__global__ __launch_bounds__(256) void k_node_mfma(
        const float* __restrict__ q,
        const unsigned short* __restrict__ iW1t,   // [128][128] bf16 (c,k)
        const float* __restrict__ b1,
        const unsigned short* __restrict__ iW2t,   // [384][128]
        const float* __restrict__ b2,
        unsigned int* __restrict__ P, int N) {
    __shared__ unsigned short A[16 * 136];
    __shared__ unsigned short Ah[16 * 136];
    __shared__ float Xs[16 * 396];
    int t = threadIdx.x;
    int w = t >> 6, l = t & 63, quad = l >> 4, c0 = l & 15;
    int n0 = blockIdx.x * 16;

#pragma unroll
    for (int i = 0; i < 4; i++) {
        int flat = i * 256 + t;
        int node = flat >> 6, cp = flat & 63;
        int gn = n0 + node;
        unsigned int v = 0u;
        if (gn < N) { const float* s = q + (size_t)gn * 128 + 2 * cp; v = pack_bf2(s[0], s[1]); }
        *(unsigned int*)&A[node * 136 + 2 * cp] = v;
    }
    __syncthreads();

    bf16x8 a1[4];
#pragma unroll
    for (int ks = 0; ks < 4; ks++)
        a1[ks] = *(const bf16x8*)&A[c0 * 136 + ks * 32 + quad * 8];
#pragma unroll
    for (int jj = 0; jj < 2; jj++) {
        int jg = 2 * w + jj;
        float bb = b1[16 * jg + c0];
        f32x4 acc = (f32x4){bb, bb, bb, bb};
#pragma unroll
        for (int ks = 0; ks < 4; ks++) {
            bf16x8 b = *(const bf16x8*)&iW1t[(16 * jg + c0) * 128 + ks * 32 + quad * 8];
            acc = __builtin_amdgcn_mfma_f32_16x16x32_bf16(a1[ks], b, acc, 0, 0, 0);
        }
#pragma unroll
        for (int r = 0; r < 4; r++) {
            float aa = acc[r];
            Ah[(quad * 4 + r) * 136 + 16 * jg + c0] =
                (unsigned short)bf16_rtne(aa / (1.f + __expf(-aa)));
        }
    }
    __syncthreads();

    bf16x8 a3[4];
#pragma unroll
    for (int ks = 0; ks < 4; ks++)
        a3[ks] = *(const bf16x8*)&Ah[c0 * 136 + ks * 32 + quad * 8];
#pragma unroll
    for (int jj = 0; jj < 6; jj++) {
        int jx = 6 * w + jj;
        float bb = b2[16 * jx + c0];
        f32x4 acc = (f32x4){bb, bb, bb, bb};
#pragma unroll
        for (int ks = 0; ks < 4; ks++) {
            bf16x8 b = *(const bf16x8*)&iW2t[(16 * jx + c0) * 128 + ks * 32 + quad * 8];
            acc = __builtin_amdgcn_mfma_f32_16x16x32_bf16(a3[ks], b, acc, 0, 0, 0);
        }
#pragma unroll
        for (int r = 0; r < 4; r++)
            Xs[(quad * 4 + r) * 396 + 16 * jx + c0] = acc[r];
    }
    __syncthreads();

    int n = t >> 4, fi = (t & 15) * 8;
    int gn = n0 + n;
    if (gn < N) {
        size_t base = (size_t)gn * 384;
        unsigned int d[8];
#pragma unroll
        for (int k = 0; k < 8; k++) {
            float x0 = Xs[n * 396 + fi + k];
            float x1 = Xs[n * 396 + 128 + fi + k];
            float x2 = Xs[n * 396 + 256 + fi + k];
            d[k] = pack_bf2(x0, x1);
            ((unsigned short*)&P[base + 256 + fi + k])[0] = (unsigned short)bf16_rtne(x2);
        }
        *(uint4*)&P[base + fi]     = make_uint4(d[0], d[1], d[2], d[3]);
        *(uint4*)&P[base + fi + 4] = make_uint4(d[4], d[5], d[6], d[7]);
    }
}

// ---------------------------------------------------------------------------
// Edge aggregation. __launch_bounds__(256,4): allow ~128 VGPRs so the
// per-thread filter weights (60 VGPRs) stay register-resident instead of
// being reloaded every edge (R8 postmortem: VGPR_Count=44 proved reloads).
__global__ __launch_bounds__(256, 4) void k_edge(
        const unsigned int* __restrict__ P,
        const float* __restrict__ geom,
        const int* __restrict__ idx_j,
        const int* __restrict__ row_ptr,
        const float* __restrict__ filt_W,
        const float* __restrict__ filt_b,
        int layer,
        float* __restrict__ q,
        float* __restrict__ muD, int N) {
    __shared__ float red[4][128];
    int t = threadIdx.x;
    int f = t & 127;
    int sub = __builtin_amdgcn_readfirstlane(t >> 7);

    v2f W0p[N_RBF / 2], W1p[N_RBF / 2], W2p[N_RBF / 2];
    const float* Wbase = filt_W + layer * 384;
#pragma unroll
    for (int j = 0; j < N_RBF / 2; j++) {
        W0p[j] = (v2f){Wbase[(2 * j) * 1152 + f],       Wbase[(2 * j + 1) * 1152 + f]};
        W1p[j] = (v2f){Wbase[(2 * j) * 1152 + 128 + f], Wbase[(2 * j + 1) * 1152 + 128 + f]};
        W2p[j] = (v2f){Wbase[(2 * j) * 1152 + 256 + f], Wbase[(2 * j + 1) * 1152 + 256 + f]};
    }
    float bf0 = filt_b[layer * 384 + f];
    float bf1 = filt_b[layer * 384 + 128 + f];
    float bf2 = filt_b[layer * 384 + 256 + f];

    int i0 = blockIdx.x * NPB;
    for (int nn = 0; nn < NPB; nn++) {
        int i = i0 + nn;
        if (i >= N) break;
        int rs = __builtin_amdgcn_readfirstlane(row_ptr[i]);
        int re = __builtin_amdgcn_readfirstlane(row_ptr[i + 1]);
        float dq = 0.f;
        v2f dm01 = (v2f){0.f, 0.f};
        float dm2 = 0.f;

        for (int e = rs + sub; e < re; e += 2) {
            int j = __builtin_amdgcn_readfirstlane(idx_j[e]);
            const unsigned int* Pj = P + (size_t)j * 384;
            unsigned int A = Pj[f];
            unsigned int B = Pj[128 + f];
            unsigned int C = Pj[256 + f];

            const float4* g4 = (const float4*)(geom + (size_t)e * 24);
            float4 a  = g4[0];
            float4 p0 = g4[1], p1 = g4[2], p2 = g4[3], p3 = g4[4], p4 = g4[5];

            v2f ph[N_RBF / 2] = {
                (v2f){p0.x, p0.y}, (v2f){p0.z, p0.w},
                (v2f){p1.x, p1.y}, (v2f){p1.z, p1.w},
                (v2f){p2.x, p2.y}, (v2f){p2.z, p2.w},
                (v2f){p3.x, p3.y}, (v2f){p3.z, p3.w},
                (v2f){p4.x, p4.y}, (v2f){p4.z, p4.w}};
            v2f aq = (v2f){0.f, 0.f}, ar = (v2f){0.f, 0.f}, am = (v2f){0.f, 0.f};
#pragma unroll
            for (int k = 0; k < N_RBF / 2; k++) {
                aq += ph[k] * W0p[k];
                ar += ph[k] * W1p[k];
                am += ph[k] * W2p[k];
            }
            float wq = aq.x + aq.y + a.w * bf0;
            float wr = ar.x + ar.y + a.w * bf1;
            float wm = am.x + am.y + a.w * bf2;

            float xq = unpk_lo(A), xr = unpk_hi(A);
            float m0 = unpk_lo(B), m1 = unpk_hi(B);
            float xm = unpk_lo(C), m2 = unpk_hi(C);

            dq += wq * xq;
            float s_r = wr * xr, s_m = wm * xm;
            dm01 += (v2f){s_r, s_r} * (v2f){a.x, a.y} + (v2f){s_m, s_m} * (v2f){m0, m1};
            dm2  += s_r * a.z + s_m * m2;
        }

        if (sub == 1) { red[0][f] = dq; red[1][f] = dm01.x; red[2][f] = dm01.y; red[3][f] = dm2; }
        __syncthreads();
        if (sub == 0) {
            dq += red[0][f];
            float d0 = dm01.x + red[1][f], d1 = dm01.y + red[2][f];
            dm2 += red[3][f];
            q[(size_t)i * 128 + f] += dq;
            size_t base = (size_t)i * 384;
            muD[base + f]       += d0;
            muD[base + 128 + f] += d1;
            muD[base + 256 + f] += dm2;
        }
        __syncthreads();
    }
}

// ---------------------------------------------------------------------------
// Fused mixing(l) + node-message(l+1) kernel. 4 waves per 16-node tile.
// Mix part identical to R8 k_mix_mfma; epilogue additionally deposits q_new
// (bf16) into A, then the node MLP for the NEXT layer runs in-block
// (has_node=1), writing the x message planes. has_node=0 -> mix only.
__global__ __launch_bounds__(256) void k_mix_fused(
        float* __restrict__ q, float* __restrict__ mu,
        const unsigned short* __restrict__ muxWt,   // [256][128] bf16 (c,k)
        const unsigned short* __restrict__ W1t,     // [128][256]
        const unsigned short* __restrict__ W2t,     // [384][128]
        const float* __restrict__ b1,
        const float* __restrict__ b2,
        const unsigned short* __restrict__ niW1t,   // next-layer node W1t
        const float* __restrict__ nib1,
        const unsigned short* __restrict__ niW2t,   // next-layer node W2t
        const float* __restrict__ nib2,
        int has_node,
        unsigned int* __restrict__ P, int N) {
    __shared__ unsigned short A[16 * 264];          // [node][K=256+pad] bf16
    __shared__ unsigned short Wsp[3 * 16 * 136];    // mu_W bf16; reused as Ah
    __shared__ float Xs[16 * 396];
    __shared__ float Ss[16 * 140];
    int t = threadIdx.x;
    int w = t >> 6, l = t & 63, quad = l >> 4, c0 = l & 15;
    int n0 = blockIdx.x * 16;

    // stage q -> A[:,0:128]
#pragma unroll
    for (int i = 0; i < 4; i++) {
        int flat = i * 256 + t;
        int node = flat >> 6, cp = flat & 63;
        int gn = n0 + node;
        unsigned int v = 0u;
        if (gn < N) { const float* s = q + (size_t)gn * 128 + 2 * cp; v = pack_bf2(s[0], s[1]); }
        *(unsigned int*)&A[node * 264 + 2 * cp] = v;
    }

    f32x4 vn2[2], S[2];
#pragma unroll
    for (int jj = 0; jj < 2; jj++) { vn2[jj] = (f32x4){0,0,0,0}; S[jj] = (f32x4){0,0,0,0}; }

    for (int c = 0; c < 3; c++) {
#pragma unroll
        for (int i = 0; i < 4; i++) {
            int flat = i * 256 + t;
            int node = flat >> 6, cp = flat & 63;
            int gn = n0 + node;
            unsigned int v = 0u;
            if (gn < N) {
                const float* s = mu + (size_t)gn * 384 + c * 128 + 2 * cp;
                v = pack_bf2(s[0], s[1]);
            }
            *(unsigned int*)&A[node * 264 + 128 + 2 * cp] = v;
        }
        __syncthreads();
        bf16x8 af[4];
#pragma unroll
        for (int ks = 0; ks < 4; ks++)
            af[ks] = *(const bf16x8*)&A[c0 * 264 + 128 + ks * 32 + quad * 8];
#pragma unroll
        for (int jj = 0; jj < 2; jj++) {
            int jv = 2 * w + jj;
            f32x4 V = (f32x4){0,0,0,0}, Wm = (f32x4){0,0,0,0};
#pragma unroll
            for (int ks = 0; ks < 4; ks++) {
                bf16x8 bV = *(const bf16x8*)&muxWt[(16 * jv + c0) * 128 + ks * 32 + quad * 8];
                V = __builtin_amdgcn_mfma_f32_16x16x32_bf16(af[ks], bV, V, 0, 0, 0);
            }
#pragma unroll
            for (int ks = 0; ks < 4; ks++) {
                bf16x8 bW = *(const bf16x8*)&muxWt[(16 * (jv + 8) + c0) * 128 + ks * 32 + quad * 8];
                Wm = __builtin_amdgcn_mfma_f32_16x16x32_bf16(af[ks], bW, Wm, 0, 0, 0);
            }
            vn2[jj] += V * V;
            S[jj]   += V * Wm;
#pragma unroll
            for (int r = 0; r < 4; r++)
                Wsp[c * 2176 + (quad * 4 + r) * 136 + 16 * jv + c0] =
                    (unsigned short)bf16_rtne(Wm[r]);
        }
        __syncthreads();
    }

    // vn -> A[:,128:256]
#pragma unroll
    for (int jj = 0; jj < 2; jj++) {
        int jv = 2 * w + jj;
#pragma unroll
        for (int r = 0; r < 4; r++)
            A[(quad * 4 + r) * 264 + 128 + 16 * jv + c0] =
                (unsigned short)bf16_rtne(sqrtf(vn2[jj][r] + 1e-8f));
    }
    __syncthreads();

    // GEMM2: h = silu([q|vn]@W1 + b1), K=256
    bf16x8 a2[8];
#pragma unroll
    for (int ks = 0; ks < 8; ks++)
        a2[ks] = *(const bf16x8*)&A[c0 * 264 + ks * 32 + quad * 8];
    {
        unsigned short htmp[2][4];
#pragma unroll
        for (int jj = 0; jj < 2; jj++) {
            int jg = 2 * w + jj;
            float bb = b1[16 * jg + c0];
            f32x4 acc = (f32x4){bb, bb, bb, bb};
#pragma unroll
            for (int ks = 0; ks < 8; ks++) {
                bf16x8 b = *(const bf16x8*)&W1t[(16 * jg + c0) * 256 + ks * 32 + quad * 8];
                acc = __builtin_amdgcn_mfma_f32_16x16x32_bf16(a2[ks], b, acc, 0, 0, 0);
            }
#pragma unroll
            for (int r = 0; r < 4; r++) {
                float aa = acc[r];
                htmp[jj][r] = (unsigned short)bf16_rtne(aa / (1.f + __expf(-aa)));
            }
        }
        __syncthreads();   // Wsp reads (mix h staging writes go to Xs-safe area)
        // store h into Ah region (reuse upper Wsp is unsafe: epilogue still
        // needs Wsp) -> stash h rows in Xs tail? No: use A[:,128:256] (vn no
        // longer needed after a2 fragments are in registers).
#pragma unroll
        for (int jj = 0; jj < 2; jj++) {
            int jg = 2 * w + jj;
#pragma unroll
            for (int r = 0; r < 4; r++)
                A[(quad * 4 + r) * 264 + 128 + 16 * jg + c0] = htmp[jj][r];
        }
    }
    __syncthreads();

    // GEMM3: x = h@W2 + b2, K=128 (h lives in A[:,128:256])
    bf16x8 a3[4];
#pragma unroll
    for (int ks = 0; ks < 4; ks++)
        a3[ks] = *(const bf16x8*)&A[c0 * 264 + 128 + ks * 32 + quad * 8];
#pragma unroll
    for (int jj = 0; jj < 6; jj++) {
        int jx = 6 * w + jj;
        float bb = b2[16 * jx + c0];
        f32x4 acc = (f32x4){bb, bb, bb, bb};
#pragma unroll
        for (int ks = 0; ks < 4; ks++) {
            bf16x8 b = *(const bf16x8*)&W2t[(16 * jx + c0) * 128 + ks * 32 + quad * 8];
            acc = __builtin_amdgcn_mfma_f32_16x16x32_bf16(a3[ks], b, acc, 0, 0, 0);
        }
#pragma unroll
        for (int r = 0; r < 4; r++)
            Xs[(quad * 4 + r) * 396 + 16 * jx + c0] = acc[r];
    }
#pragma unroll
    for (int jj = 0; jj < 2; jj++) {
        int jv = 2 * w + jj;
#pragma unroll
        for (int r = 0; r < 4; r++)
            Ss[(quad * 4 + r) * 140 + 16 * jv + c0] = S[jj][r];
    }
    __syncthreads();

    // mix epilogue: update q/mu, write mu message planes, deposit q_new in A
    int n = t >> 4, fi = (t & 15) * 8;
    int gn = n0 + n;
    if (gn < N) {
        float* qp = q + (size_t)gn * 128 + fi;
        float qn[8];
#pragma unroll
        for (int k = 0; k < 8; k++) {
            qn[k] = qp[k] + Xs[n * 396 + fi + k] +
                    Xs[n * 396 + 256 + fi + k] * Ss[n * 140 + fi + k];
            qp[k] = qn[k];
        }
        unsigned int qd[4];
#pragma unroll
        for (int p = 0; p < 4; p++) qd[p] = pack_bf2(qn[2 * p], qn[2 * p + 1]);
        *(uint4*)&A[n * 264 + fi] = make_uint4(qd[0], qd[1], qd[2], qd[3]);

        size_t base = (size_t)gn * 384;
        float m[3][8];
#pragma unroll
        for (int c = 0; c < 3; c++) {
            float* mp = mu + base + c * 128 + fi;
#pragma unroll
            for (int k = 0; k < 8; k++) {
                m[c][k] = mp[k] + Xs[n * 396 + 128 + fi + k] *
                                  bf16_to_f(Wsp[c * 2176 + n * 136 + fi + k]);
                mp[k] = m[c][k];
            }
        }
        unsigned int d[8];
#pragma unroll
        for (int k = 0; k < 8; k++) {
            d[k] = pack_bf2(m[0][k], m[1][k]);
            ((unsigned short*)&P[base + 256 + fi + k])[1] = (unsigned short)bf16_rtne(m[2][k]);
        }
        *(uint4*)&P[base + 128 + fi]     = make_uint4(d[0], d[1], d[2], d[3]);
        *(uint4*)&P[base + 128 + fi + 4] = make_uint4(d[4], d[5], d[6], d[7]);
    }
    __syncthreads();

    if (has_node) {
        // node MLP for next layer on q_new (A[:,0:128])
        unsigned short* Ah = Wsp;   // reuse (Wsp dead now)
        bf16x8 a1[4];
#pragma unroll
        for (int ks = 0; ks < 4; ks++)
            a1[ks] = *(const bf16x8*)&A[c0 * 264 + ks * 32 + quad * 8];
#pragma unroll
        for (int jj = 0; jj < 2; jj++) {
            int jg = 2 * w + jj;
            float bb = nib1[16 * jg + c0];
            f32x4 acc = (f32x4){bb, bb, bb, bb};
#pragma unroll
            for (int ks = 0; ks < 4; ks++) {
                bf16x8 b = *(const bf16x8*)&niW1t[(16 * jg + c0) * 128 + ks * 32 + quad * 8];
                acc = __builtin_amdgcn_mfma_f32_16x16x32_bf16(a1[ks], b, acc, 0, 0, 0);
            }
#pragma unroll
            for (int r = 0; r < 4; r++) {
                float aa = acc[r];
                Ah[(quad * 4 + r) * 136 + 16 * jg + c0] =
                    (unsigned short)bf16_rtne(aa / (1.f + __expf(-aa)));
            }
        }
        __syncthreads();

        bf16x8 a4[4];
#pragma unroll
        for (int ks = 0; ks < 4; ks++)
            a4[ks] = *(const bf16x8*)&Ah[c0 * 136 + ks * 32 + quad * 8];
#pragma unroll
        for (int jj = 0; jj < 6; jj++) {
            int jx = 6 * w + jj;
            float bb = nib2[16 * jx + c0];
            f32x4 acc = (f32x4){bb, bb, bb, bb};
#pragma unroll
            for (int ks = 0; ks < 4; ks++) {
                bf16x8 b = *(const bf16x8*)&niW2t[(16 * jx + c0) * 128 + ks * 32 + quad * 8];
                acc = __builtin_amdgcn_mfma_f32_16x16x32_bf16(a4[ks], b, acc, 0, 0, 0);
            }
#pragma unroll
            for (int r = 0; r < 4; r++)
                Xs[(quad * 4 + r) * 396 + 16 * jx + c0] = acc[r];
        }
        __syncthreads();

        if (gn < N) {
            size_t base = (size_t)gn * 384;
            unsigned int d[8];
#pragma unroll
            for (int k = 0; k < 8; k++) {
                float x0 = Xs[n * 396 + fi + k];
                float x1 = Xs[n * 396 + 128 + fi + k];
                float x2 = Xs[n * 396 + 256 + fi + k];
                d[k] = pack_bf2(x0, x1);
                ((unsigned short*)&P[base + 256 + fi + k])[0] = (unsigned short)bf16_rtne(x2);
            }
            *(uint4*)&P[base + fi]     = make_uint4(d[0], d[1], d[2], d[3]);
            *(uint4*)&P[base + fi + 4] = make_uint4(d[4], d[5], d[6], d[7]);
        }
    }
}

// ---------------------------------------------------------------------------
extern "C" void kernel_launch(void* const* d_in, const int* in_sizes, int n_in,
                              void* d_out, int out_size, void* d_ws, size_t ws_size,
                              hipStream_t stream) {
    const int*   Z      = (const int*)d_in[0];
    const float* r_ij   = (const float*)d_in[1];
    const int*   idx_i  = (const int*)d_in[2];
    const int*   idx_j  = (const int*)d_in[3];
    const float* emb    = (const float*)d_in[4];
    const float* filt_W = (const float*)d_in[5];
    const float* filt_b = (const float*)d_in[6];
    const float* int_W1 = (const float*)d_in[7];
    const float* int_b1 = (const float*)d_in[8];
    const float* int_W2 = (const float*)d_in[9];
    const float* int_b2 = (const float*)d_in[10];
    const float* mix_W1 = (const float*)d_in[11];
    const float* mix_b1 = (const float*)d_in[12];
    const float* mix_W2 = (const float*)d_in[13];
    const float* mix_b2 = (const float*)d_in[14];
    const float* mux_W  = (const float*)d_in[15];

    int N = in_sizes[0];
    int E = in_sizes[2];

    float* q   = (float*)d_out;              // [N,128]  q state (fp32)
    float* muD = q + (size_t)N * 128;        // [N,3,128] mu state (fp32)

    float* ws   = (float*)d_ws;
    float* geom = ws;                            // E*24 fp32
    unsigned int* P = (unsigned int*)(geom + (size_t)E * 24);  // N*384 u32
    int* row_ptr = (int*)(P + (size_t)N * 384);  // N+1
    uintptr_t waddr = (uintptr_t)(row_ptr + N + 1);
    waddr = (waddr + 15) & ~(uintptr_t)15;
    unsigned short* muxWt = (unsigned short*)waddr;   // 3*256*128
    unsigned short* W1t   = muxWt + 98304;            // 3*128*256
    unsigned short* W2t   = W1t + 98304;              // 3*384*128
    unsigned short* iW1t  = W2t + 147456;             // 3*128*128
    unsigned short* iW2t  = iW1t + 49152;             // 3*384*128

    k_rowptr<<<(N + 1 + 255) / 256, 256, 0, stream>>>(idx_i, row_ptr, N, E);
    k_init<<<((size_t)N * 384 + 255) / 256, 256, 0, stream>>>(Z, emb, q, P, muD, N);
    k_geom<<<(E + 255) / 256, 256, 0, stream>>>(r_ij, geom, E);
    k_prep<<<2112, 256, 0, stream>>>(mux_W, mix_W1, mix_W2, int_W1, int_W2,
                                     muxWt, W1t, W2t, iW1t, iW2t);

    int tiles = (N + 15) / 16;
    // layer 0 node MLP standalone; later node MLPs fused into mix
    k_node_mfma<<<tiles, 256, 0, stream>>>(
        q, iW1t, int_b1, iW2t, int_b2, P, N);
    for (int l = 0; l < 3; l++) {
        k_edge<<<(N + NPB - 1) / NPB, 256, 0, stream>>>(
            P, geom, idx_j, row_ptr, filt_W, filt_b, l, q, muD, N);
        int nl = (l < 2) ? (l + 1) : 0;
        k_mix_fused<<<tiles, 256, 0, stream>>>(
            q, muD, muxWt + (size_t)l * 32768, W1t + (size_t)l * 32768,
            W2t + (size_t)l * 49152, mix_b1 + l * 128, mix_b2 + l * 384,
            iW1t + (size_t)nl * 16384, int_b1 + nl * 128,
            iW2t + (size_t)nl * 49152, int_b2 + nl * 384,
            (l < 2) ? 1 : 0, P, N);
    }
    // q in d_out; final mu (fp32 state) in muD = d_out mu region.
}